// Round 7
// baseline (249.815 us; speedup 1.0000x reference)
//
#include <hip/hip_runtime.h>
#include <cstddef>

#define NROWS 65536
#define DIN   512
#define ZDIM  128
#define KCB   1024

typedef float  f32x4  __attribute__((ext_vector_type(4)));
typedef short  short8 __attribute__((ext_vector_type(8)));
typedef __bf16 bf16x8 __attribute__((ext_vector_type(8)));
typedef unsigned short ushort_t;
typedef unsigned int   uint_t;
typedef unsigned long long u64_t;

// ---- ws layout ----
#define CB_CHB 24576
#define CB_SPB 8192
#define W_CHB  24576
#define W_SPB  8192
#define CNORM_OFF 786432
#define WF_OFF    790528
#define WS_NEEDED (790528 + 393216)

#define POOL_CAP 192

__device__ inline ushort_t bf_rtn(float v) {
  uint_t u = __float_as_uint(v);
  uint_t r = (u + 0x7fffu + ((u >> 16) & 1u)) >> 16;
  return (ushort_t)r;
}
__device__ inline float bf_up(ushort_t b) { return __uint_as_float(((uint_t)b) << 16); }
__device__ inline bf16x8 as_bf(short8 s) {
  union { short8 s; bf16x8 b; } u; u.s = s; return u.b;
}
__device__ inline void split3(float v, ushort_t& s1, ushort_t& s2, ushort_t& s3) {
  s1 = bf_rtn(v);  float f1 = bf_up(s1);
  float r1 = v - f1; s2 = bf_rtn(r1); float f2 = bf_up(s2);
  float r2 = r1 - f2; s3 = bf_rtn(r2);
}

// exact f32 refinement of one (row, col) candidate; CAS-min into rowkey[r]
__device__ inline void refine_one(uint_t packed, int bm, int w,
    const float* __restrict__ zc, const float* __restrict__ cbk,
    const float* __restrict__ cnorm, u64_t* rowkey)
{
  const int col = packed & 1023;
  const int rowloc = (packed >> 10) & 31;
  const int r = w * 32 + rowloc;
  const float* zr = zc + ((size_t)bm * 128 + r) * ZDIM;
  const float* cr = cbk + (size_t)col * ZDIM;
  f32x4 dps = {0.f, 0.f, 0.f, 0.f}, aps = {0.f, 0.f, 0.f, 0.f};
#pragma unroll
  for (int u = 0; u < 32; ++u) {
    f32x4 zv = *(const f32x4*)(zr + u * 4);
    f32x4 cv = *(const f32x4*)(cr + u * 4);
    dps += zv * cv;
    aps += zv * zv;
  }
  float dot = (dps[0] + dps[1]) + (dps[2] + dps[3]);
  float A   = (aps[0] + aps[1]) + (aps[2] + aps[3]);
  float d = (A - 2.f * dot) + cnorm[col];
  uint_t db = __float_as_uint(d);
  db = (db & 0x80000000u) ? ~db : (db | 0x80000000u);   // monotone float->uint
  u64_t key = ((u64_t)db << 32) | (uint_t)col;
  u64_t old = rowkey[r];
  while (key < old) {
    u64_t assumed = old;
    old = atomicCAS(&rowkey[r], assumed, key);
    if (old == assumed) break;
  }
}

// ---------------------------------------------------------------------------
// ksplit2: codebook -> fragment-contiguous 3-way bf16 split + ||c||^2
// ---------------------------------------------------------------------------
__global__ __launch_bounds__(128) void ksplit2(
    const float* __restrict__ cbk, char* __restrict__ wsb)
{
  const int n = blockIdx.x, k = threadIdx.x;
  float v = cbk[(size_t)n * ZDIM + k];
  ushort_t s1, s2, s3; split3(v, s1, s2, s3);

  const int chunk = n >> 5, ct = (n >> 4) & 1;
  const int km = k & 31, ks = k >> 5;
  const int g = (km >> 2) & 3, h = (km >> 4) & 1, j = (km & 3) + 4 * h;
  const int l = 16 * g + (n & 15);
  char* base = wsb + chunk * CB_CHB + ct * 4096 + ks * 1024 + l * 16 + j * 2;
  *(ushort_t*)(base + 0 * CB_SPB) = s1;
  *(ushort_t*)(base + 1 * CB_SPB) = s2;
  *(ushort_t*)(base + 2 * CB_SPB) = s3;

  float c2 = v * v;
#pragma unroll
  for (int m = 1; m < 64; m <<= 1) c2 += __shfl_xor(c2, m);
  __shared__ float wsum[2];
  if ((threadIdx.x & 63) == 0) wsum[threadIdx.x >> 6] = c2;
  __syncthreads();
  if (threadIdx.x == 0)
    *(float*)(wsb + CNORM_OFF + (size_t)n * 4) = wsum[0] + wsum[1];
}

// ---------------------------------------------------------------------------
// wsplit: W -> fragment-contiguous 3-way bf16 split
// ---------------------------------------------------------------------------
__global__ __launch_bounds__(256) void wsplit(
    const float* __restrict__ W, char* __restrict__ wsb)
{
  const int idx = blockIdx.x * 256 + threadIdx.x;
  const int k = idx >> 7, col = idx & 127;
  float v = W[(size_t)k * ZDIM + col];
  ushort_t s1, s2, s3; split3(v, s1, s2, s3);

  const int kc = k >> 5, km = k & 31;
  const int g = (km >> 2) & 3, h = (km >> 4) & 1, j = (km & 3) + 4 * h;
  const int ct = col >> 4, l = 16 * g + (col & 15);
  char* base = wsb + WF_OFF + kc * W_CHB + ct * 1024 + l * 16 + j * 2;
  *(ushort_t*)(base + 0 * W_SPB) = s1;
  *(ushort_t*)(base + 1 * W_SPB) = s2;
  *(ushort_t*)(base + 2 * W_SPB) = s3;
}

// ---------------------------------------------------------------------------
// k1f: grid 768. Blocks 0..511: round-3 GEMM (z = x@W+b, 6-product MFMA,
// LDS dbuf, 1 barrier/chunk). Blocks 512..767: barrier-free streaming fill
// of the one-hot zeros (268 MB) — co-resident waves overlap the GEMM.
// ---------------------------------------------------------------------------
__global__ __launch_bounds__(256, 2) void k1f(
    const float* __restrict__ x, const char* __restrict__ wfs,
    const float* __restrict__ b, float* __restrict__ z,
    float* __restrict__ oh)
{
  __shared__ __align__(16) char wbuf[2 * W_CHB];   // 48 KB

  if (blockIdx.x >= 512) {
    // ---- one-hot zero fill: 256 blocks x 256 thr x 256 f32x4 ----
    const size_t tid = (size_t)(blockIdx.x - 512) * 256 + threadIdx.x;
    const f32x4 zv = {0.f, 0.f, 0.f, 0.f};
    f32x4* dst = (f32x4*)oh + tid;
#pragma unroll 8
    for (int it = 0; it < 256; ++it)
      __builtin_nontemporal_store(zv, dst + (size_t)it * 65536);
    return;
  }

  const int t = threadIdx.x, w = t >> 6, l = t & 63;
  const int g = l >> 4, c16 = l & 15;
  const int bm = blockIdx.x;

  f32x4 acc[2][8];
#pragma unroll
  for (int rt = 0; rt < 2; ++rt)
#pragma unroll
    for (int ct = 0; ct < 8; ++ct) acc[rt][ct] = (f32x4){0.f, 0.f, 0.f, 0.f};

  const size_t rowb[2] = {
    ((size_t)bm * 128 + w * 32 + 0 * 16 + c16) * DIN,
    ((size_t)bm * 128 + w * 32 + 1 * 16 + c16) * DIN };

  f32x4 wreg[6];
#pragma unroll
  for (int it = 0; it < 6; ++it)
    wreg[it] = *(const f32x4*)(wfs + it * 4096 + t * 16);
  f32x4 xcur[2][2];
#pragma unroll
  for (int rt = 0; rt < 2; ++rt)
#pragma unroll
    for (int h = 0; h < 2; ++h)
      xcur[rt][h] = *(const f32x4*)(x + rowb[rt] + 4 * g + 16 * h);
#pragma unroll
  for (int it = 0; it < 6; ++it)
    *(f32x4*)(wbuf + it * 4096 + t * 16) = wreg[it];
  __syncthreads();

  for (int kc = 0; kc < 16; ++kc) {
    const char* buf = wbuf + (size_t)(kc & 1) * W_CHB;
    const bool more = (kc + 1) < 16;
    f32x4 xnext[2][2];
    if (more) {
#pragma unroll
      for (int it = 0; it < 6; ++it)
        wreg[it] = *(const f32x4*)(wfs + (size_t)(kc + 1) * W_CHB + it * 4096 + t * 16);
#pragma unroll
      for (int rt = 0; rt < 2; ++rt)
#pragma unroll
        for (int h = 0; h < 2; ++h)
          xnext[rt][h] = *(const f32x4*)(x + rowb[rt] + (kc + 1) * 32 + 4 * g + 16 * h);
    }

    short8 a1[2], a2[2], a3[2];
#pragma unroll
    for (int rt = 0; rt < 2; ++rt)
#pragma unroll
      for (int h = 0; h < 2; ++h)
#pragma unroll
        for (int j = 0; j < 4; ++j) {
          ushort_t q1, q2, q3; split3(xcur[rt][h][j], q1, q2, q3);
          a1[rt][4 * h + j] = (short)q1;
          a2[rt][4 * h + j] = (short)q2;
          a3[rt][4 * h + j] = (short)q3;
        }

#pragma unroll
    for (int ct = 0; ct < 8; ++ct) {
      const char* bp = buf + ct * 1024 + l * 16;
      short8 b1 = *(const short8*)(bp + 0 * W_SPB);
      short8 b2 = *(const short8*)(bp + 1 * W_SPB);
      short8 b3 = *(const short8*)(bp + 2 * W_SPB);
#pragma unroll
      for (int rt = 0; rt < 2; ++rt) {
        f32x4 a = acc[rt][ct];
        a = __builtin_amdgcn_mfma_f32_16x16x32_bf16(as_bf(a1[rt]), as_bf(b1), a, 0, 0, 0);
        a = __builtin_amdgcn_mfma_f32_16x16x32_bf16(as_bf(a1[rt]), as_bf(b2), a, 0, 0, 0);
        a = __builtin_amdgcn_mfma_f32_16x16x32_bf16(as_bf(a2[rt]), as_bf(b1), a, 0, 0, 0);
        a = __builtin_amdgcn_mfma_f32_16x16x32_bf16(as_bf(a1[rt]), as_bf(b3), a, 0, 0, 0);
        a = __builtin_amdgcn_mfma_f32_16x16x32_bf16(as_bf(a2[rt]), as_bf(b2), a, 0, 0, 0);
        a = __builtin_amdgcn_mfma_f32_16x16x32_bf16(as_bf(a3[rt]), as_bf(b1), a, 0, 0, 0);
        acc[rt][ct] = a;
      }
    }

    if (more) {
      char* nbuf = wbuf + (size_t)((kc + 1) & 1) * W_CHB;
#pragma unroll
      for (int it = 0; it < 6; ++it)
        *(f32x4*)(nbuf + it * 4096 + t * 16) = wreg[it];
#pragma unroll
      for (int rt = 0; rt < 2; ++rt)
#pragma unroll
        for (int h = 0; h < 2; ++h) xcur[rt][h] = xnext[rt][h];
    }
    __syncthreads();
  }

  // epilogue: bias + store z
#pragma unroll
  for (int ct = 0; ct < 8; ++ct) {
    float bb = b[ct * 16 + c16];
#pragma unroll
    for (int rt = 0; rt < 2; ++rt)
#pragma unroll
      for (int i = 0; i < 4; ++i) {
        size_t row = (size_t)bm * 128 + w * 32 + rt * 16 + 4 * g + i;
        z[row * ZDIM + ct * 16 + c16] = acc[rt][ct][i] + bb;
      }
  }
}

// ---------------------------------------------------------------------------
// k2f1: single-pass candidate-filtered VQ.
// Per chunk: s1*s1 MFMA approx distances -> update running min (cross-lane
// shared) -> gate f <= runmin + T, pool candidates -> exact f32 refine with
// u64 CAS-min (first-index tie-break) -> outputs.
// ---------------------------------------------------------------------------
__global__ __launch_bounds__(256, 2) void k2f1(
    const float* __restrict__ zc, const float* __restrict__ cbk,
    const char* __restrict__ cbs, const float* __restrict__ cnorm,
    float* __restrict__ zst, float* __restrict__ zq, float* __restrict__ oh)
{
  __shared__ __align__(16) char sm[16384];   // s1 chunk double buffer (2 x 8 KB)
  __shared__ u64_t rowkey[128];
  __shared__ uint_t wpool[4][POOL_CAP];
  __shared__ int wcnt[4];
  __shared__ int karr[128];

  const int t = threadIdx.x, w = t >> 6, l = t & 63;
  const int g = l >> 4, c16 = l & 15;
  const int bm = blockIdx.x;

  if (t < 128) rowkey[t] = ~0ull;
  if (t < 4) wcnt[t] = 0;

  // ---- A-frags (s1 only) + exact row norms ----
  short8 a1f[2][4];
  float anorm[2][4];
#pragma unroll
  for (int rt = 0; rt < 2; ++rt) {
    const size_t rb = ((size_t)bm * 128 + w * 32 + rt * 16 + c16) * ZDIM;
    float psum = 0.f;
#pragma unroll
    for (int ks = 0; ks < 4; ++ks)
#pragma unroll
      for (int h = 0; h < 2; ++h) {
        f32x4 v = *(const f32x4*)(zc + rb + ks * 32 + 4 * g + 16 * h);
#pragma unroll
        for (int j = 0; j < 4; ++j) {
          a1f[rt][ks][4 * h + j] = (short)bf_rtn(v[j]);
          psum += v[j] * v[j];
        }
      }
    psum += __shfl_xor(psum, 16);
    psum += __shfl_xor(psum, 32);
#pragma unroll
    for (int i = 0; i < 4; ++i) anorm[rt][i] = __shfl(psum, 4 * g + i);
  }

  float thr_add[2][4];
  float m1[2][4];
#pragma unroll
  for (int rt = 0; rt < 2; ++rt)
#pragma unroll
    for (int i = 0; i < 4; ++i) {
      thr_add[rt][i] = 0.25f * sqrtf(anorm[rt][i]);
      m1[rt][i] = 3.402823466e38f;
    }

  // prologue: stage chunk 0
  f32x4 streg[2];
#pragma unroll
  for (int it = 0; it < 2; ++it)
    streg[it] = *(const f32x4*)(cbs + it * 4096 + t * 16);
#pragma unroll
  for (int it = 0; it < 2; ++it)
    *(f32x4*)(sm + it * 4096 + t * 16) = streg[it];
  __syncthreads();

  for (int c = 0; c < 32; ++c) {
    const char* buf = sm + (size_t)(c & 1) * 8192;
    const bool more = (c + 1) < 32;
    if (more) {
#pragma unroll
      for (int it = 0; it < 2; ++it)
        streg[it] = *(const f32x4*)(cbs + (size_t)(c + 1) * CB_CHB + it * 4096 + t * 16);
    }
    const float cn0 = cnorm[c * 32 + c16];
    const float cn1 = cnorm[c * 32 + 16 + c16];

    // compute the 16 approx distances for this chunk
    float fv[2][2][4];     // [ct][rt][i]
#pragma unroll
    for (int ct = 0; ct < 2; ++ct) {
      f32x4 pa[2];
#pragma unroll
      for (int rt = 0; rt < 2; ++rt) pa[rt] = (f32x4){0.f, 0.f, 0.f, 0.f};
#pragma unroll
      for (int ks = 0; ks < 4; ++ks) {
        short8 b1 = *(const short8*)(buf + ct * 4096 + ks * 1024 + l * 16);
#pragma unroll
        for (int rt = 0; rt < 2; ++rt)
          pa[rt] = __builtin_amdgcn_mfma_f32_16x16x32_bf16(as_bf(a1f[rt][ks]), as_bf(b1), pa[rt], 0, 0, 0);
      }
      const float cn = ct ? cn1 : cn0;
#pragma unroll
      for (int rt = 0; rt < 2; ++rt)
#pragma unroll
        for (int i = 0; i < 4; ++i) {
          float f = (anorm[rt][i] - 2.f * pa[rt][i]) + cn;
          fv[ct][rt][i] = f;
          m1[rt][i] = fminf(m1[rt][i], f);
        }
    }

    // share running min across the 16-lane col group
#pragma unroll
    for (int m = 1; m < 16; m <<= 1)
#pragma unroll
      for (int rt = 0; rt < 2; ++rt)
#pragma unroll
        for (int i = 0; i < 4; ++i)
          m1[rt][i] = fminf(m1[rt][i], __shfl_xor(m1[rt][i], m));

    // gate + pool
#pragma unroll
    for (int ct = 0; ct < 2; ++ct) {
      const int colb = c * 32 + ct * 16 + c16;
#pragma unroll
      for (int rt = 0; rt < 2; ++rt)
#pragma unroll
        for (int i = 0; i < 4; ++i) {
          if (fv[ct][rt][i] <= m1[rt][i] + thr_add[rt][i]) {
            uint_t packed = (uint_t)colb | ((uint_t)(rt * 16 + 4 * g + i) << 10);
            int slot = atomicAdd(&wcnt[w], 1);
            if (slot < POOL_CAP) wpool[w][slot] = packed;
            else refine_one(packed, bm, w, zc, cbk, cnorm, rowkey);
          }
        }
    }

    if (more) {
      char* nbuf = sm + (size_t)((c + 1) & 1) * 8192;
#pragma unroll
      for (int it = 0; it < 2; ++it)
        *(f32x4*)(nbuf + it * 4096 + t * 16) = streg[it];
    }
    __syncthreads();
  }

  // ================= refine (wave-pooled, lane-parallel) =================
  int cnt = wcnt[w]; if (cnt > POOL_CAP) cnt = POOL_CAP;
  for (int s = l; s < cnt; s += 64)
    refine_one(wpool[w][s], bm, w, zc, cbk, cnorm, rowkey);
  __syncthreads();
  if (t < 128) karr[t] = (int)(rowkey[t] & 1023ull);
  __syncthreads();

  // ---- zst + zq (vectorized gather from L2-resident codebook) ----
#pragma unroll
  for (int it = 0; it < 16; ++it) {
    const int idx = it * 256 + t;
    const int r = idx >> 5, cq = (idx & 31) * 4;
    f32x4 v = *(const f32x4*)&cbk[(size_t)karr[r] * ZDIM + cq];
    const size_t off = ((size_t)bm * 128 + r) * ZDIM + cq;
    __builtin_nontemporal_store(v, (f32x4*)(zst + off));
    __builtin_nontemporal_store(v, (f32x4*)(zq + off));
  }

  // ---- one-hot 1.0 scatter (zeros written by k1f's fill blocks) ----
  if (t < 128) {
    oh[(size_t)(bm * 128 + t) * KCB + karr[t]] = 1.0f;
  }
}

// ---------------------------------------------------------------------------
// Fallback path (ws too small): round-1 f32 kernels
// ---------------------------------------------------------------------------
__global__ __launch_bounds__(256) void k1_gemm(
    const float* __restrict__ x, const float* __restrict__ W,
    const float* __restrict__ b, float* __restrict__ z)
{
  __shared__ float xs[32][68];
  __shared__ float ws[32][132];

  const int t  = threadIdx.x;
  const int tx = t & 15, ty = t >> 4;
  const int bm = blockIdx.x;

  float acc[4][8];
#pragma unroll
  for (int i = 0; i < 4; ++i)
#pragma unroll
    for (int j = 0; j < 8; ++j) acc[i][j] = 0.f;

  const int sr  = t >> 2;
  const int skb = (t & 3) * 8;
  const int wkk = t >> 3;
  const int wcol = (t & 7) * 16;

  for (int k0 = 0; k0 < DIN; k0 += 32) {
    float4 v0 = *reinterpret_cast<const float4*>(&x[(size_t)(bm * 64 + sr) * DIN + k0 + skb]);
    float4 v1 = *reinterpret_cast<const float4*>(&x[(size_t)(bm * 64 + sr) * DIN + k0 + skb + 4]);
    xs[skb + 0][sr] = v0.x; xs[skb + 1][sr] = v0.y; xs[skb + 2][sr] = v0.z; xs[skb + 3][sr] = v0.w;
    xs[skb + 4][sr] = v1.x; xs[skb + 5][sr] = v1.y; xs[skb + 6][sr] = v1.z; xs[skb + 7][sr] = v1.w;
#pragma unroll
    for (int u = 0; u < 4; ++u) {
      float4 wv = *reinterpret_cast<const float4*>(&W[(size_t)(k0 + wkk) * ZDIM + wcol + u * 4]);
      *reinterpret_cast<float4*>(&ws[wkk][wcol + u * 4]) = wv;
    }
    __syncthreads();
#pragma unroll
    for (int kk = 0; kk < 32; ++kk) {
      float4 xv = *reinterpret_cast<float4*>(&xs[kk][ty * 4]);
      float4 wa = *reinterpret_cast<float4*>(&ws[kk][tx * 4]);
      float4 wb = *reinterpret_cast<float4*>(&ws[kk][64 + tx * 4]);
      float xr[4] = {xv.x, xv.y, xv.z, xv.w};
      float wr[8] = {wa.x, wa.y, wa.z, wa.w, wb.x, wb.y, wb.z, wb.w};
#pragma unroll
      for (int i = 0; i < 4; ++i)
#pragma unroll
        for (int j = 0; j < 8; ++j) acc[i][j] += xr[i] * wr[j];
    }
    __syncthreads();
  }

  float4 ba = *reinterpret_cast<const float4*>(&b[tx * 4]);
  float4 bb = *reinterpret_cast<const float4*>(&b[64 + tx * 4]);
#pragma unroll
  for (int i = 0; i < 4; ++i) {
    size_t row = (size_t)bm * 64 + ty * 4 + i;
    float4 oa = {acc[i][0] + ba.x, acc[i][1] + ba.y, acc[i][2] + ba.z, acc[i][3] + ba.w};
    float4 ob = {acc[i][4] + bb.x, acc[i][5] + bb.y, acc[i][6] + bb.z, acc[i][7] + bb.w};
    *reinterpret_cast<float4*>(&z[row * ZDIM + tx * 4]) = oa;
    *reinterpret_cast<float4*>(&z[row * ZDIM + 64 + tx * 4]) = ob;
  }
}

__global__ __launch_bounds__(256) void k2_vq(
    const float* __restrict__ zc, const float* __restrict__ cbk,
    float* __restrict__ zst, float* __restrict__ zq, float* __restrict__ oh)
{
  __shared__ float zt[128][68];
  __shared__ float ct[32][132];
  __shared__ float pc[128][2];
  __shared__ float csqc[128];
  __shared__ float Ap[64][4];
  __shared__ float Al[64];
  __shared__ float fbuf[64][17];
  __shared__ int   ibuf[64][17];
  __shared__ int   karr[64];

  const int t  = threadIdx.x;
  const int tx = t & 15, ty = t >> 4;
  const int bm = blockIdx.x;

  {
    const int r = t >> 2, kb = (t & 3) * 32;
    float asum = 0.f;
#pragma unroll
    for (int u = 0; u < 8; ++u) {
      float4 v = *reinterpret_cast<const float4*>(&zc[(size_t)(bm * 64 + r) * ZDIM + kb + u * 4]);
      zt[kb + u * 4 + 0][r] = v.x; zt[kb + u * 4 + 1][r] = v.y;
      zt[kb + u * 4 + 2][r] = v.z; zt[kb + u * 4 + 3][r] = v.w;
      asum += v.x * v.x + v.y * v.y + v.z * v.z + v.w * v.w;
    }
    Ap[r][t & 3] = asum;
  }
  __syncthreads();
  if (t < 64) Al[t] = (Ap[t][0] + Ap[t][1]) + (Ap[t][2] + Ap[t][3]);

  float fmin[4];
  int   kmin[4];
#pragma unroll
  for (int i = 0; i < 4; ++i) { fmin[i] = 3.4e38f; kmin[i] = 0; }

  const int scol = t >> 1, skb = (t & 1) * 16;

  for (int chunk = 0; chunk < 8; ++chunk) {
    float acc[4][8];
#pragma unroll
    for (int i = 0; i < 4; ++i)
#pragma unroll
      for (int j = 0; j < 8; ++j) acc[i][j] = 0.f;
    float cpart = 0.f;

    for (int ks = 0; ks < 4; ++ks) {
      __syncthreads();
#pragma unroll
      for (int u = 0; u < 4; ++u) {
        float4 v = *reinterpret_cast<const float4*>(
            &cbk[(size_t)(chunk * 128 + scol) * ZDIM + ks * 32 + skb + u * 4]);
        ct[skb + u * 4 + 0][scol] = v.x; ct[skb + u * 4 + 1][scol] = v.y;
        ct[skb + u * 4 + 2][scol] = v.z; ct[skb + u * 4 + 3][scol] = v.w;
        cpart += v.x * v.x + v.y * v.y + v.z * v.z + v.w * v.w;
      }
      __syncthreads();
#pragma unroll
      for (int kk = 0; kk < 32; ++kk) {
        float4 xv = *reinterpret_cast<float4*>(&zt[ks * 32 + kk][ty * 4]);
        float4 wa = *reinterpret_cast<float4*>(&ct[kk][tx * 4]);
        float4 wb = *reinterpret_cast<float4*>(&ct[kk][64 + tx * 4]);
        float xr[4] = {xv.x, xv.y, xv.z, xv.w};
        float wr[8] = {wa.x, wa.y, wa.z, wa.w, wb.x, wb.y, wb.z, wb.w};
#pragma unroll
        for (int i = 0; i < 4; ++i)
#pragma unroll
          for (int j = 0; j < 8; ++j) acc[i][j] += xr[i] * wr[j];
      }
    }

    pc[scol][t & 1] = cpart;
    __syncthreads();
    if (t < 128) csqc[t] = pc[t][0] + pc[t][1];
    __syncthreads();

#pragma unroll
    for (int i = 0; i < 4; ++i) {
      float Ar = Al[ty * 4 + i];
#pragma unroll
      for (int j = 0; j < 8; ++j) {
        int colL = (j < 4) ? (tx * 4 + j) : (64 + tx * 4 + (j - 4));
        float B = 2.f * acc[i][j];
        float f = (Ar - B) + csqc[colL];
        int col = chunk * 128 + colL;
        if (f < fmin[i] || (f == fmin[i] && col < kmin[i])) { fmin[i] = f; kmin[i] = col; }
      }
    }
  }

#pragma unroll
  for (int i = 0; i < 4; ++i) { fbuf[ty * 4 + i][tx] = fmin[i]; ibuf[ty * 4 + i][tx] = kmin[i]; }
  __syncthreads();
  if (t < 64) {
    float bf = fbuf[t][0]; int bi = ibuf[t][0];
    for (int e = 1; e < 16; ++e) {
      float f2 = fbuf[t][e]; int i2 = ibuf[t][e];
      if (f2 < bf || (f2 == bf && i2 < bi)) { bf = f2; bi = i2; }
    }
    karr[t] = bi;
  }
  __syncthreads();

  for (int it = 0; it < 32; ++it) {
    int r = it * 2 + (t >> 7);
    int col = t & 127;
    size_t row = (size_t)bm * 64 + r;
    float v = cbk[(size_t)karr[r] * ZDIM + col];
    zst[row * ZDIM + col] = v;
    zq[row * ZDIM + col] = v;
  }

  for (int r = 0; r < 64; ++r) {
    int k = karr[r];
    float4 v = {0.f, 0.f, 0.f, 0.f};
    if ((k >> 2) == t) {
      float* vv = reinterpret_cast<float*>(&v);
      vv[k & 3] = 1.f;
    }
    *reinterpret_cast<float4*>(&oh[(size_t)(bm * 64 + r) * KCB + t * 4]) = v;
  }
}

extern "C" void kernel_launch(void* const* d_in, const int* in_sizes, int n_in,
                              void* d_out, int out_size, void* d_ws, size_t ws_size,
                              hipStream_t stream) {
  const float* x   = (const float*)d_in[0];
  const float* W   = (const float*)d_in[1];
  const float* b   = (const float*)d_in[2];
  const float* cbk = (const float*)d_in[3];

  float* out = (float*)d_out;
  float* zst = out;
  float* zq  = out + (size_t)NROWS * ZDIM;
  float* zc  = out + (size_t)2 * NROWS * ZDIM;
  float* oh  = out + (size_t)3 * NROWS * ZDIM;

  if (ws_size >= (size_t)WS_NEEDED) {
    char* wsb = (char*)d_ws;
    ksplit2<<<KCB, 128, 0, stream>>>(cbk, wsb);
    wsplit<<<256, 256, 0, stream>>>(W, wsb);
    k1f<<<768, 256, 0, stream>>>(x, wsb + WF_OFF, b, zc, oh);
    k2f1<<<NROWS / 128, 256, 0, stream>>>(
        zc, cbk, wsb, (const float*)(wsb + CNORM_OFF), zst, zq, oh);
  } else {
    k1_gemm<<<NROWS / 64, 256, 0, stream>>>(x, W, b, zc);
    k2_vq<<<NROWS / 64, 256, 0, stream>>>(zc, cbk, zst, zq, oh);
  }
}

// Round 8
// 212.507 us; speedup vs baseline: 1.1756x; 1.1756x over previous
//
#include <hip/hip_runtime.h>
#include <cstddef>

#define NROWS 65536
#define DIN   512
#define ZDIM  128
#define KCB   1024

typedef float  f32x4  __attribute__((ext_vector_type(4)));
typedef short  short8 __attribute__((ext_vector_type(8)));
typedef __bf16 bf16x8 __attribute__((ext_vector_type(8)));
typedef unsigned short ushort_t;
typedef unsigned int   uint_t;
typedef unsigned long long u64_t;

// ---- ws layout ----
#define CB_CHB 24576
#define CB_SPB 8192
#define W_CHB  24576
#define W_SPB  8192
#define CNORM_OFF 786432
#define WF_OFF    790528
#define WS_NEEDED (790528 + 393216)

#define POOL_CAP 128

__device__ inline ushort_t bf_rtn(float v) {
  uint_t u = __float_as_uint(v);
  uint_t r = (u + 0x7fffu + ((u >> 16) & 1u)) >> 16;
  return (ushort_t)r;
}
__device__ inline float bf_up(ushort_t b) { return __uint_as_float(((uint_t)b) << 16); }
__device__ inline bf16x8 as_bf(short8 s) {
  union { short8 s; bf16x8 b; } u; u.s = s; return u.b;
}
__device__ inline void split3(float v, ushort_t& s1, ushort_t& s2, ushort_t& s3) {
  s1 = bf_rtn(v);  float f1 = bf_up(s1);
  float r1 = v - f1; s2 = bf_rtn(r1); float f2 = bf_up(s2);
  float r2 = r1 - f2; s3 = bf_rtn(r2);
}

// exact f32 refinement of one (row, col) candidate; CAS-min into rowkey[r]
__device__ inline void refine_one(uint_t packed, int bm, int w,
    const float* __restrict__ zc, const float* __restrict__ cbk,
    const float* __restrict__ cnorm, u64_t* rowkey)
{
  const int col = packed & 1023;
  const int rowloc = (packed >> 10) & 31;
  const int r = w * 32 + rowloc;
  const float* zr = zc + ((size_t)bm * 128 + r) * ZDIM;
  const float* cr = cbk + (size_t)col * ZDIM;
  f32x4 dps = {0.f, 0.f, 0.f, 0.f}, aps = {0.f, 0.f, 0.f, 0.f};
#pragma unroll
  for (int u = 0; u < 32; ++u) {
    f32x4 zv = *(const f32x4*)(zr + u * 4);
    f32x4 cv = *(const f32x4*)(cr + u * 4);
    dps += zv * cv;
    aps += zv * zv;
  }
  float dot = (dps[0] + dps[1]) + (dps[2] + dps[3]);
  float A   = (aps[0] + aps[1]) + (aps[2] + aps[3]);
  float d = (A - 2.f * dot) + cnorm[col];
  uint_t db = __float_as_uint(d);
  db = (db & 0x80000000u) ? ~db : (db | 0x80000000u);   // monotone float->uint
  u64_t key = ((u64_t)db << 32) | (uint_t)col;
  u64_t old = rowkey[r];
  while (key < old) {
    u64_t assumed = old;
    old = atomicCAS(&rowkey[r], assumed, key);
    if (old == assumed) break;
  }
}

// ---------------------------------------------------------------------------
// prep: merged codebook + W 3-way bf16 split (+ ||c||^2).
// grid 1536 x 128: blocks 0..1023 = codebook row n; 1024..1535 = W elements.
// ---------------------------------------------------------------------------
__global__ __launch_bounds__(128) void prep(
    const float* __restrict__ cbk, const float* __restrict__ W,
    char* __restrict__ wsb)
{
  if (blockIdx.x < 1024) {
    const int n = blockIdx.x, k = threadIdx.x;
    float v = cbk[(size_t)n * ZDIM + k];
    ushort_t s1, s2, s3; split3(v, s1, s2, s3);

    const int chunk = n >> 5, ct = (n >> 4) & 1;
    const int km = k & 31, ks = k >> 5;
    const int g = (km >> 2) & 3, h = (km >> 4) & 1, j = (km & 3) + 4 * h;
    const int l = 16 * g + (n & 15);
    char* base = wsb + chunk * CB_CHB + ct * 4096 + ks * 1024 + l * 16 + j * 2;
    *(ushort_t*)(base + 0 * CB_SPB) = s1;
    *(ushort_t*)(base + 1 * CB_SPB) = s2;
    *(ushort_t*)(base + 2 * CB_SPB) = s3;

    float c2 = v * v;
#pragma unroll
    for (int m = 1; m < 64; m <<= 1) c2 += __shfl_xor(c2, m);
    __shared__ float wsum[2];
    if ((threadIdx.x & 63) == 0) wsum[threadIdx.x >> 6] = c2;
    __syncthreads();
    if (threadIdx.x == 0)
      *(float*)(wsb + CNORM_OFF + (size_t)n * 4) = wsum[0] + wsum[1];
  } else {
    const int idx = (blockIdx.x - 1024) * 128 + threadIdx.x;   // 0..65535
    const int k = idx >> 7, col = idx & 127;
    float v = W[(size_t)k * ZDIM + col];
    ushort_t s1, s2, s3; split3(v, s1, s2, s3);

    const int kc = k >> 5, km = k & 31;
    const int g = (km >> 2) & 3, h = (km >> 4) & 1, j = (km & 3) + 4 * h;
    const int ct = col >> 4, l = 16 * g + (col & 15);
    char* base = wsb + WF_OFF + kc * W_CHB + ct * 1024 + l * 16 + j * 2;
    *(ushort_t*)(base + 0 * W_SPB) = s1;
    *(ushort_t*)(base + 1 * W_SPB) = s2;
    *(ushort_t*)(base + 2 * W_SPB) = s3;
  }
}

// ---------------------------------------------------------------------------
// k1_oh: z = x@W+b via 6-product MFMA + interleaved one-hot zero writes.
// launch_bounds(256,3): 3 blocks/CU (48KB LDS x3 = 144 <= 160) for TLP.
// ---------------------------------------------------------------------------
__global__ __launch_bounds__(256, 3) void k1_oh(
    const float* __restrict__ x, const char* __restrict__ wfs,
    const float* __restrict__ b, float* __restrict__ z,
    float* __restrict__ oh)
{
  __shared__ __align__(16) char wbuf[2 * W_CHB];   // 48 KB

  const int t = threadIdx.x, w = t >> 6, l = t & 63;
  const int g = l >> 4, c16 = l & 15;
  const int bm = blockIdx.x;

  f32x4 acc[2][8];
#pragma unroll
  for (int rt = 0; rt < 2; ++rt)
#pragma unroll
    for (int ct = 0; ct < 8; ++ct) acc[rt][ct] = (f32x4){0.f, 0.f, 0.f, 0.f};

  const size_t rowb[2] = {
    ((size_t)bm * 128 + w * 32 + 0 * 16 + c16) * DIN,
    ((size_t)bm * 128 + w * 32 + 1 * 16 + c16) * DIN };

  f32x4 wreg[6];
#pragma unroll
  for (int it = 0; it < 6; ++it)
    wreg[it] = *(const f32x4*)(wfs + it * 4096 + t * 16);
  f32x4 xcur[2][2];
#pragma unroll
  for (int rt = 0; rt < 2; ++rt)
#pragma unroll
    for (int h = 0; h < 2; ++h)
      xcur[rt][h] = *(const f32x4*)(x + rowb[rt] + 4 * g + 16 * h);
#pragma unroll
  for (int it = 0; it < 6; ++it)
    *(f32x4*)(wbuf + it * 4096 + t * 16) = wreg[it];
  __syncthreads();

  for (int kc = 0; kc < 16; ++kc) {
    const char* buf = wbuf + (size_t)(kc & 1) * W_CHB;
    const bool more = (kc + 1) < 16;
    f32x4 xnext[2][2];
    if (more) {
#pragma unroll
      for (int it = 0; it < 6; ++it)
        wreg[it] = *(const f32x4*)(wfs + (size_t)(kc + 1) * W_CHB + it * 4096 + t * 16);
#pragma unroll
      for (int rt = 0; rt < 2; ++rt)
#pragma unroll
        for (int h = 0; h < 2; ++h)
          xnext[rt][h] = *(const f32x4*)(x + rowb[rt] + (kc + 1) * 32 + 4 * g + 16 * h);
    }

    // one-hot zeros for rows kc*8 .. kc*8+7 (streams under the MFMA block)
    {
      float* orow = oh + ((size_t)bm * 128 + kc * 8 + (t >> 5)) * KCB + (t & 31) * 4;
      const f32x4 zv4 = {0.f, 0.f, 0.f, 0.f};
#pragma unroll
      for (int u = 0; u < 8; ++u)
        __builtin_nontemporal_store(zv4, (f32x4*)(orow + u * 128));
    }

    short8 a1[2], a2[2], a3[2];
#pragma unroll
    for (int rt = 0; rt < 2; ++rt)
#pragma unroll
      for (int h = 0; h < 2; ++h)
#pragma unroll
        for (int j = 0; j < 4; ++j) {
          ushort_t q1, q2, q3; split3(xcur[rt][h][j], q1, q2, q3);
          a1[rt][4 * h + j] = (short)q1;
          a2[rt][4 * h + j] = (short)q2;
          a3[rt][4 * h + j] = (short)q3;
        }

#pragma unroll
    for (int ct = 0; ct < 8; ++ct) {
      const char* bp = buf + ct * 1024 + l * 16;
      short8 b1 = *(const short8*)(bp + 0 * W_SPB);
      short8 b2 = *(const short8*)(bp + 1 * W_SPB);
      short8 b3 = *(const short8*)(bp + 2 * W_SPB);
#pragma unroll
      for (int rt = 0; rt < 2; ++rt) {
        f32x4 a = acc[rt][ct];
        a = __builtin_amdgcn_mfma_f32_16x16x32_bf16(as_bf(a1[rt]), as_bf(b1), a, 0, 0, 0);
        a = __builtin_amdgcn_mfma_f32_16x16x32_bf16(as_bf(a1[rt]), as_bf(b2), a, 0, 0, 0);
        a = __builtin_amdgcn_mfma_f32_16x16x32_bf16(as_bf(a2[rt]), as_bf(b1), a, 0, 0, 0);
        a = __builtin_amdgcn_mfma_f32_16x16x32_bf16(as_bf(a1[rt]), as_bf(b3), a, 0, 0, 0);
        a = __builtin_amdgcn_mfma_f32_16x16x32_bf16(as_bf(a2[rt]), as_bf(b2), a, 0, 0, 0);
        a = __builtin_amdgcn_mfma_f32_16x16x32_bf16(as_bf(a3[rt]), as_bf(b1), a, 0, 0, 0);
        acc[rt][ct] = a;
      }
    }

    if (more) {
      char* nbuf = wbuf + (size_t)((kc + 1) & 1) * W_CHB;
#pragma unroll
      for (int it = 0; it < 6; ++it)
        *(f32x4*)(nbuf + it * 4096 + t * 16) = wreg[it];
#pragma unroll
      for (int rt = 0; rt < 2; ++rt)
#pragma unroll
        for (int h = 0; h < 2; ++h) xcur[rt][h] = xnext[rt][h];
    }
    __syncthreads();
  }

  // epilogue: bias + store z
#pragma unroll
  for (int ct = 0; ct < 8; ++ct) {
    float bb = b[ct * 16 + c16];
#pragma unroll
    for (int rt = 0; rt < 2; ++rt)
#pragma unroll
      for (int i = 0; i < 4; ++i) {
        size_t row = (size_t)bm * 128 + w * 32 + rt * 16 + 4 * g + i;
        z[row * ZDIM + ct * 16 + c16] = acc[rt][ct][i] + bb;
      }
  }
}

// ---------------------------------------------------------------------------
// k2f: two-pass candidate-filtered VQ (round-6 proven structure).
//  pass 1: s1*s1 MFMA -> per-row approx min m^
//  pass 2: replay, gate d^ <= m^ + 0.25*sqrt(A), pool candidates
//  refine: exact f32 dot, u64 CAS-min (first-index tie-break). Then outputs.
// launch_bounds(256,4): 4 blocks/CU for latency hiding (LDS ~20KB).
// ---------------------------------------------------------------------------
__global__ __launch_bounds__(256, 4) void k2f(
    const float* __restrict__ zc, const float* __restrict__ cbk,
    const char* __restrict__ cbs, const float* __restrict__ cnorm,
    float* __restrict__ zst, float* __restrict__ zq, float* __restrict__ oh)
{
  __shared__ __align__(16) char sm[16384];   // s1 chunk double buffer (2 x 8 KB)
  __shared__ u64_t rowkey[128];
  __shared__ uint_t wpool[4][POOL_CAP];
  __shared__ int wcnt[4];
  __shared__ int karr[128];

  const int t = threadIdx.x, w = t >> 6, l = t & 63;
  const int g = l >> 4, c16 = l & 15;
  const int bm = blockIdx.x;

  if (t < 128) rowkey[t] = ~0ull;
  if (t < 4) wcnt[t] = 0;

  // ---- A-frags (s1 only) + exact row norms ----
  short8 a1f[2][4];
  float anorm[2][4];
#pragma unroll
  for (int rt = 0; rt < 2; ++rt) {
    const size_t rb = ((size_t)bm * 128 + w * 32 + rt * 16 + c16) * ZDIM;
    float psum = 0.f;
#pragma unroll
    for (int ks = 0; ks < 4; ++ks)
#pragma unroll
      for (int h = 0; h < 2; ++h) {
        f32x4 v = *(const f32x4*)(zc + rb + ks * 32 + 4 * g + 16 * h);
#pragma unroll
        for (int j = 0; j < 4; ++j) {
          a1f[rt][ks][4 * h + j] = (short)bf_rtn(v[j]);
          psum += v[j] * v[j];
        }
      }
    psum += __shfl_xor(psum, 16);
    psum += __shfl_xor(psum, 32);
#pragma unroll
    for (int i = 0; i < 4; ++i) anorm[rt][i] = __shfl(psum, 4 * g + i);
  }

  // ================= pass 1: approx min =================
  float m1[2][4];
#pragma unroll
  for (int rt = 0; rt < 2; ++rt)
#pragma unroll
    for (int i = 0; i < 4; ++i) m1[rt][i] = 3.402823466e38f;

  f32x4 streg[2];
#pragma unroll
  for (int it = 0; it < 2; ++it)
    streg[it] = *(const f32x4*)(cbs + it * 4096 + t * 16);
#pragma unroll
  for (int it = 0; it < 2; ++it)
    *(f32x4*)(sm + it * 4096 + t * 16) = streg[it];
  __syncthreads();

  for (int c = 0; c < 32; ++c) {
    const char* buf = sm + (size_t)(c & 1) * 8192;
    const bool more = (c + 1) < 32;
    if (more) {
#pragma unroll
      for (int it = 0; it < 2; ++it)
        streg[it] = *(const f32x4*)(cbs + (size_t)(c + 1) * CB_CHB + it * 4096 + t * 16);
    }
    const float cn0 = cnorm[c * 32 + c16];
    const float cn1 = cnorm[c * 32 + 16 + c16];

#pragma unroll
    for (int ct = 0; ct < 2; ++ct) {
      f32x4 pa[2];
#pragma unroll
      for (int rt = 0; rt < 2; ++rt) pa[rt] = (f32x4){0.f, 0.f, 0.f, 0.f};
#pragma unroll
      for (int ks = 0; ks < 4; ++ks) {
        short8 b1 = *(const short8*)(buf + ct * 4096 + ks * 1024 + l * 16);
#pragma unroll
        for (int rt = 0; rt < 2; ++rt)
          pa[rt] = __builtin_amdgcn_mfma_f32_16x16x32_bf16(as_bf(a1f[rt][ks]), as_bf(b1), pa[rt], 0, 0, 0);
      }
      const float cn = ct ? cn1 : cn0;
#pragma unroll
      for (int rt = 0; rt < 2; ++rt)
#pragma unroll
        for (int i = 0; i < 4; ++i) {
          float f = (anorm[rt][i] - 2.f * pa[rt][i]) + cn;
          m1[rt][i] = fminf(m1[rt][i], f);
        }
    }

    if (more) {
      char* nbuf = sm + (size_t)((c + 1) & 1) * 8192;
#pragma unroll
      for (int it = 0; it < 2; ++it)
        *(f32x4*)(nbuf + it * 4096 + t * 16) = streg[it];
    }
    __syncthreads();
  }

  // cross-lane min within each 16-lane group
#pragma unroll
  for (int m = 1; m < 16; m <<= 1)
#pragma unroll
    for (int rt = 0; rt < 2; ++rt)
#pragma unroll
      for (int i = 0; i < 4; ++i)
        m1[rt][i] = fminf(m1[rt][i], __shfl_xor(m1[rt][i], m));

  float thr[2][4];
#pragma unroll
  for (int rt = 0; rt < 2; ++rt)
#pragma unroll
    for (int i = 0; i < 4; ++i)
      thr[rt][i] = m1[rt][i] + 0.25f * sqrtf(anorm[rt][i]);

  // ================= pass 2: collect candidates =================
#pragma unroll
  for (int it = 0; it < 2; ++it)
    streg[it] = *(const f32x4*)(cbs + it * 4096 + t * 16);
#pragma unroll
  for (int it = 0; it < 2; ++it)
    *(f32x4*)(sm + it * 4096 + t * 16) = streg[it];
  __syncthreads();

  for (int c = 0; c < 32; ++c) {
    const char* buf = sm + (size_t)(c & 1) * 8192;
    const bool more = (c + 1) < 32;
    if (more) {
#pragma unroll
      for (int it = 0; it < 2; ++it)
        streg[it] = *(const f32x4*)(cbs + (size_t)(c + 1) * CB_CHB + it * 4096 + t * 16);
    }
    const float cn0 = cnorm[c * 32 + c16];
    const float cn1 = cnorm[c * 32 + 16 + c16];

#pragma unroll
    for (int ct = 0; ct < 2; ++ct) {
      f32x4 pa[2];
#pragma unroll
      for (int rt = 0; rt < 2; ++rt) pa[rt] = (f32x4){0.f, 0.f, 0.f, 0.f};
#pragma unroll
      for (int ks = 0; ks < 4; ++ks) {
        short8 b1 = *(const short8*)(buf + ct * 4096 + ks * 1024 + l * 16);
#pragma unroll
        for (int rt = 0; rt < 2; ++rt)
          pa[rt] = __builtin_amdgcn_mfma_f32_16x16x32_bf16(as_bf(a1f[rt][ks]), as_bf(b1), pa[rt], 0, 0, 0);
      }
      const float cn = ct ? cn1 : cn0;
      const int colb = c * 32 + ct * 16 + c16;
#pragma unroll
      for (int rt = 0; rt < 2; ++rt)
#pragma unroll
        for (int i = 0; i < 4; ++i) {
          float f = (anorm[rt][i] - 2.f * pa[rt][i]) + cn;
          if (f <= thr[rt][i]) {
            uint_t packed = (uint_t)colb | ((uint_t)(rt * 16 + 4 * g + i) << 10);
            int slot = atomicAdd(&wcnt[w], 1);
            if (slot < POOL_CAP) wpool[w][slot] = packed;
            else refine_one(packed, bm, w, zc, cbk, cnorm, rowkey);  // rare
          }
        }
    }

    if (more) {
      char* nbuf = sm + (size_t)((c + 1) & 1) * 8192;
#pragma unroll
      for (int it = 0; it < 2; ++it)
        *(f32x4*)(nbuf + it * 4096 + t * 16) = streg[it];
    }
    __syncthreads();
  }

  // ================= refine (wave-pooled, lane-parallel) =================
  int cnt = wcnt[w]; if (cnt > POOL_CAP) cnt = POOL_CAP;
  for (int s = l; s < cnt; s += 64)
    refine_one(wpool[w][s], bm, w, zc, cbk, cnorm, rowkey);
  __syncthreads();
  if (t < 128) karr[t] = (int)(rowkey[t] & 1023ull);
  __syncthreads();

  // ---- zst + zq (vectorized gather from L2-resident codebook) ----
#pragma unroll
  for (int it = 0; it < 16; ++it) {
    const int idx = it * 256 + t;
    const int r = idx >> 5, cq = (idx & 31) * 4;
    f32x4 v = *(const f32x4*)&cbk[(size_t)karr[r] * ZDIM + cq];
    const size_t off = ((size_t)bm * 128 + r) * ZDIM + cq;
    __builtin_nontemporal_store(v, (f32x4*)(zst + off));
    __builtin_nontemporal_store(v, (f32x4*)(zq + off));
  }

  // ---- one-hot 1.0 scatter (zeros written by k1_oh) ----
  if (t < 128) {
    oh[(size_t)(bm * 128 + t) * KCB + karr[t]] = 1.0f;
  }
}

// ---------------------------------------------------------------------------
// Fallback path (ws too small): round-1 f32 kernels
// ---------------------------------------------------------------------------
__global__ __launch_bounds__(256) void k1_gemm(
    const float* __restrict__ x, const float* __restrict__ W,
    const float* __restrict__ b, float* __restrict__ z)
{
  __shared__ float xs[32][68];
  __shared__ float ws[32][132];

  const int t  = threadIdx.x;
  const int tx = t & 15, ty = t >> 4;
  const int bm = blockIdx.x;

  float acc[4][8];
#pragma unroll
  for (int i = 0; i < 4; ++i)
#pragma unroll
    for (int j = 0; j < 8; ++j) acc[i][j] = 0.f;

  const int sr  = t >> 2;
  const int skb = (t & 3) * 8;
  const int wkk = t >> 3;
  const int wcol = (t & 7) * 16;

  for (int k0 = 0; k0 < DIN; k0 += 32) {
    float4 v0 = *reinterpret_cast<const float4*>(&x[(size_t)(bm * 64 + sr) * DIN + k0 + skb]);
    float4 v1 = *reinterpret_cast<const float4*>(&x[(size_t)(bm * 64 + sr) * DIN + k0 + skb + 4]);
    xs[skb + 0][sr] = v0.x; xs[skb + 1][sr] = v0.y; xs[skb + 2][sr] = v0.z; xs[skb + 3][sr] = v0.w;
    xs[skb + 4][sr] = v1.x; xs[skb + 5][sr] = v1.y; xs[skb + 6][sr] = v1.z; xs[skb + 7][sr] = v1.w;
#pragma unroll
    for (int u = 0; u < 4; ++u) {
      float4 wv = *reinterpret_cast<const float4*>(&W[(size_t)(k0 + wkk) * ZDIM + wcol + u * 4]);
      *reinterpret_cast<float4*>(&ws[wkk][wcol + u * 4]) = wv;
    }
    __syncthreads();
#pragma unroll
    for (int kk = 0; kk < 32; ++kk) {
      float4 xv = *reinterpret_cast<float4*>(&xs[kk][ty * 4]);
      float4 wa = *reinterpret_cast<float4*>(&ws[kk][tx * 4]);
      float4 wb = *reinterpret_cast<float4*>(&ws[kk][64 + tx * 4]);
      float xr[4] = {xv.x, xv.y, xv.z, xv.w};
      float wr[8] = {wa.x, wa.y, wa.z, wa.w, wb.x, wb.y, wb.z, wb.w};
#pragma unroll
      for (int i = 0; i < 4; ++i)
#pragma unroll
        for (int j = 0; j < 8; ++j) acc[i][j] += xr[i] * wr[j];
    }
    __syncthreads();
  }

  float4 ba = *reinterpret_cast<const float4*>(&b[tx * 4]);
  float4 bb = *reinterpret_cast<const float4*>(&b[64 + tx * 4]);
#pragma unroll
  for (int i = 0; i < 4; ++i) {
    size_t row = (size_t)bm * 64 + ty * 4 + i;
    float4 oa = {acc[i][0] + ba.x, acc[i][1] + ba.y, acc[i][2] + ba.z, acc[i][3] + ba.w};
    float4 ob = {acc[i][4] + bb.x, acc[i][5] + bb.y, acc[i][6] + bb.z, acc[i][7] + bb.w};
    *reinterpret_cast<float4*>(&z[row * ZDIM + tx * 4]) = oa;
    *reinterpret_cast<float4*>(&z[row * ZDIM + 64 + tx * 4]) = ob;
  }
}

__global__ __launch_bounds__(256) void k2_vq(
    const float* __restrict__ zc, const float* __restrict__ cbk,
    float* __restrict__ zst, float* __restrict__ zq, float* __restrict__ oh)
{
  __shared__ float zt[128][68];
  __shared__ float ct[32][132];
  __shared__ float pc[128][2];
  __shared__ float csqc[128];
  __shared__ float Ap[64][4];
  __shared__ float Al[64];
  __shared__ float fbuf[64][17];
  __shared__ int   ibuf[64][17];
  __shared__ int   karr[64];

  const int t  = threadIdx.x;
  const int tx = t & 15, ty = t >> 4;
  const int bm = blockIdx.x;

  {
    const int r = t >> 2, kb = (t & 3) * 32;
    float asum = 0.f;
#pragma unroll
    for (int u = 0; u < 8; ++u) {
      float4 v = *reinterpret_cast<const float4*>(&zc[(size_t)(bm * 64 + r) * ZDIM + kb + u * 4]);
      zt[kb + u * 4 + 0][r] = v.x; zt[kb + u * 4 + 1][r] = v.y;
      zt[kb + u * 4 + 2][r] = v.z; zt[kb + u * 4 + 3][r] = v.w;
      asum += v.x * v.x + v.y * v.y + v.z * v.z + v.w * v.w;
    }
    Ap[r][t & 3] = asum;
  }
  __syncthreads();
  if (t < 64) Al[t] = (Ap[t][0] + Ap[t][1]) + (Ap[t][2] + Ap[t][3]);

  float fmin[4];
  int   kmin[4];
#pragma unroll
  for (int i = 0; i < 4; ++i) { fmin[i] = 3.4e38f; kmin[i] = 0; }

  const int scol = t >> 1, skb = (t & 1) * 16;

  for (int chunk = 0; chunk < 8; ++chunk) {
    float acc[4][8];
#pragma unroll
    for (int i = 0; i < 4; ++i)
#pragma unroll
      for (int j = 0; j < 8; ++j) acc[i][j] = 0.f;
    float cpart = 0.f;

    for (int ks = 0; ks < 4; ++ks) {
      __syncthreads();
#pragma unroll
      for (int u = 0; u < 4; ++u) {
        float4 v = *reinterpret_cast<const float4*>(
            &cbk[(size_t)(chunk * 128 + scol) * ZDIM + ks * 32 + skb + u * 4]);
        ct[skb + u * 4 + 0][scol] = v.x; ct[skb + u * 4 + 1][scol] = v.y;
        ct[skb + u * 4 + 2][scol] = v.z; ct[skb + u * 4 + 3][scol] = v.w;
        cpart += v.x * v.x + v.y * v.y + v.z * v.z + v.w * v.w;
      }
      __syncthreads();
#pragma unroll
      for (int kk = 0; kk < 32; ++kk) {
        float4 xv = *reinterpret_cast<float4*>(&zt[ks * 32 + kk][ty * 4]);
        float4 wa = *reinterpret_cast<float4*>(&ct[kk][tx * 4]);
        float4 wb = *reinterpret_cast<float4*>(&ct[kk][64 + tx * 4]);
        float xr[4] = {xv.x, xv.y, xv.z, xv.w};
        float wr[8] = {wa.x, wa.y, wa.z, wa.w, wb.x, wb.y, wb.z, wb.w};
#pragma unroll
        for (int i = 0; i < 4; ++i)
#pragma unroll
          for (int j = 0; j < 8; ++j) acc[i][j] += xr[i] * wr[j];
      }
    }

    pc[scol][t & 1] = cpart;
    __syncthreads();
    if (t < 128) csqc[t] = pc[t][0] + pc[t][1];
    __syncthreads();

#pragma unroll
    for (int i = 0; i < 4; ++i) {
      float Ar = Al[ty * 4 + i];
#pragma unroll
      for (int j = 0; j < 8; ++j) {
        int colL = (j < 4) ? (tx * 4 + j) : (64 + tx * 4 + (j - 4));
        float B = 2.f * acc[i][j];
        float f = (Ar - B) + csqc[colL];
        int col = chunk * 128 + colL;
        if (f < fmin[i] || (f == fmin[i] && col < kmin[i])) { fmin[i] = f; kmin[i] = col; }
      }
    }
  }

#pragma unroll
  for (int i = 0; i < 4; ++i) { fbuf[ty * 4 + i][tx] = fmin[i]; ibuf[ty * 4 + i][tx] = kmin[i]; }
  __syncthreads();
  if (t < 64) {
    float bf = fbuf[t][0]; int bi = ibuf[t][0];
    for (int e = 1; e < 16; ++e) {
      float f2 = fbuf[t][e]; int i2 = ibuf[t][e];
      if (f2 < bf || (f2 == bf && i2 < bi)) { bf = f2; bi = i2; }
    }
    karr[t] = bi;
  }
  __syncthreads();

  for (int it = 0; it < 32; ++it) {
    int r = it * 2 + (t >> 7);
    int col = t & 127;
    size_t row = (size_t)bm * 64 + r;
    float v = cbk[(size_t)karr[r] * ZDIM + col];
    zst[row * ZDIM + col] = v;
    zq[row * ZDIM + col] = v;
  }

  for (int r = 0; r < 64; ++r) {
    int k = karr[r];
    float4 v = {0.f, 0.f, 0.f, 0.f};
    if ((k >> 2) == t) {
      float* vv = reinterpret_cast<float*>(&v);
      vv[k & 3] = 1.f;
    }
    *reinterpret_cast<float4*>(&oh[(size_t)(bm * 64 + r) * KCB + t * 4]) = v;
  }
}

extern "C" void kernel_launch(void* const* d_in, const int* in_sizes, int n_in,
                              void* d_out, int out_size, void* d_ws, size_t ws_size,
                              hipStream_t stream) {
  const float* x   = (const float*)d_in[0];
  const float* W   = (const float*)d_in[1];
  const float* b   = (const float*)d_in[2];
  const float* cbk = (const float*)d_in[3];

  float* out = (float*)d_out;
  float* zst = out;
  float* zq  = out + (size_t)NROWS * ZDIM;
  float* zc  = out + (size_t)2 * NROWS * ZDIM;
  float* oh  = out + (size_t)3 * NROWS * ZDIM;

  if (ws_size >= (size_t)WS_NEEDED) {
    char* wsb = (char*)d_ws;
    prep<<<1536, 128, 0, stream>>>(cbk, x ? (const float*)d_in[1] : (const float*)d_in[1], wsb);
    k1_oh<<<NROWS / 128, 256, 0, stream>>>(x, wsb + WF_OFF, b, zc, oh);
    k2f<<<NROWS / 128, 256, 0, stream>>>(
        zc, cbk, wsb, (const float*)(wsb + CNORM_OFF), zst, zq, oh);
  } else {
    k1_gemm<<<NROWS / 64, 256, 0, stream>>>(x, W, b, zc);
    k2_vq<<<NROWS / 64, 256, 0, stream>>>(zc, cbk, zst, zq, oh);
  }
}

// Round 9
// 148.853 us; speedup vs baseline: 1.6783x; 1.4276x over previous
//
#include <hip/hip_runtime.h>
#include <cstddef>

#define NROWS 65536
#define DIN   512
#define ZDIM  128
#define KCB   1024

typedef float  f32x4  __attribute__((ext_vector_type(4)));
typedef short  short8 __attribute__((ext_vector_type(8)));
typedef __bf16 bf16x8 __attribute__((ext_vector_type(8)));
typedef unsigned short ushort_t;
typedef unsigned int   uint_t;
typedef unsigned long long u64_t;

// ---- ws layout ----
#define CB_CHB 24576
#define CB_SPB 8192
#define W_CHB  24576
#define W_SPB  8192
#define CNORM_OFF 786432
#define WF_OFF    790528
#define WS_NEEDED (790528 + 393216)

#define POOL_CAP 128

__device__ inline ushort_t bf_rtn(float v) {
  uint_t u = __float_as_uint(v);
  uint_t r = (u + 0x7fffu + ((u >> 16) & 1u)) >> 16;
  return (ushort_t)r;
}
__device__ inline float bf_up(ushort_t b) { return __uint_as_float(((uint_t)b) << 16); }
__device__ inline bf16x8 as_bf(short8 s) {
  union { short8 s; bf16x8 b; } u; u.s = s; return u.b;
}
__device__ inline void split3(float v, ushort_t& s1, ushort_t& s2, ushort_t& s3) {
  s1 = bf_rtn(v);  float f1 = bf_up(s1);
  float r1 = v - f1; s2 = bf_rtn(r1); float f2 = bf_up(s2);
  float r2 = r1 - f2; s3 = bf_rtn(r2);
}

// producer-side barrier: LDS writes visible, but global stores stay in flight
// (HIP __syncthreads would emit s_waitcnt vmcnt(0) and drain our nt stores).
__device__ inline void barrier_lds_only() {
  asm volatile("s_waitcnt lgkmcnt(0)" ::: "memory");
  __builtin_amdgcn_s_barrier();
}

// exact f32 refinement of one (row, col) candidate; CAS-min into rowkey[r]
__device__ inline void refine_one(uint_t packed, int bm, int w,
    const float* __restrict__ zc, const float* __restrict__ cbk,
    const float* __restrict__ cnorm, u64_t* rowkey)
{
  const int col = packed & 1023;
  const int rowloc = (packed >> 10) & 31;
  const int r = w * 32 + rowloc;
  const float* zr = zc + ((size_t)bm * 128 + r) * ZDIM;
  const float* cr = cbk + (size_t)col * ZDIM;
  f32x4 dps = {0.f, 0.f, 0.f, 0.f}, aps = {0.f, 0.f, 0.f, 0.f};
#pragma unroll
  for (int u = 0; u < 32; ++u) {
    f32x4 zv = *(const f32x4*)(zr + u * 4);
    f32x4 cv = *(const f32x4*)(cr + u * 4);
    dps += zv * cv;
    aps += zv * zv;
  }
  float dot = (dps[0] + dps[1]) + (dps[2] + dps[3]);
  float A   = (aps[0] + aps[1]) + (aps[2] + aps[3]);
  float d = (A - 2.f * dot) + cnorm[col];
  uint_t db = __float_as_uint(d);
  db = (db & 0x80000000u) ? ~db : (db | 0x80000000u);   // monotone float->uint
  u64_t key = ((u64_t)db << 32) | (uint_t)col;
  u64_t old = rowkey[r];
  while (key < old) {
    u64_t assumed = old;
    old = atomicCAS(&rowkey[r], assumed, key);
    if (old == assumed) break;
  }
}

// ---------------------------------------------------------------------------
// ksplit2: codebook -> fragment-contiguous 3-way bf16 split + ||c||^2
// ---------------------------------------------------------------------------
__global__ __launch_bounds__(128) void ksplit2(
    const float* __restrict__ cbk, char* __restrict__ wsb)
{
  const int n = blockIdx.x, k = threadIdx.x;
  float v = cbk[(size_t)n * ZDIM + k];
  ushort_t s1, s2, s3; split3(v, s1, s2, s3);

  const int chunk = n >> 5, ct = (n >> 4) & 1;
  const int km = k & 31, ks = k >> 5;
  const int g = (km >> 2) & 3, h = (km >> 4) & 1, j = (km & 3) + 4 * h;
  const int l = 16 * g + (n & 15);
  char* base = wsb + chunk * CB_CHB + ct * 4096 + ks * 1024 + l * 16 + j * 2;
  *(ushort_t*)(base + 0 * CB_SPB) = s1;
  *(ushort_t*)(base + 1 * CB_SPB) = s2;
  *(ushort_t*)(base + 2 * CB_SPB) = s3;

  float c2 = v * v;
#pragma unroll
  for (int m = 1; m < 64; m <<= 1) c2 += __shfl_xor(c2, m);
  __shared__ float wsum[2];
  if ((threadIdx.x & 63) == 0) wsum[threadIdx.x >> 6] = c2;
  __syncthreads();
  if (threadIdx.x == 0)
    *(float*)(wsb + CNORM_OFF + (size_t)n * 4) = wsum[0] + wsum[1];
}

// ---------------------------------------------------------------------------
// wsplit: W -> fragment-contiguous 3-way bf16 split
// ---------------------------------------------------------------------------
__global__ __launch_bounds__(256) void wsplit(
    const float* __restrict__ W, char* __restrict__ wsb)
{
  const int idx = blockIdx.x * 256 + threadIdx.x;
  const int k = idx >> 7, col = idx & 127;
  float v = W[(size_t)k * ZDIM + col];
  ushort_t s1, s2, s3; split3(v, s1, s2, s3);

  const int kc = k >> 5, km = k & 31;
  const int g = (km >> 2) & 3, h = (km >> 4) & 1, j = (km & 3) + 4 * h;
  const int ct = col >> 4, l = 16 * g + (col & 15);
  char* base = wsb + WF_OFF + kc * W_CHB + ct * 1024 + l * 16 + j * 2;
  *(ushort_t*)(base + 0 * W_SPB) = s1;
  *(ushort_t*)(base + 1 * W_SPB) = s2;
  *(ushort_t*)(base + 2 * W_SPB) = s3;
}

// ---------------------------------------------------------------------------
// k1_oh: z = x@W+b via 6-product MFMA + interleaved one-hot zero writes.
// In-loop barrier is lgkmcnt-only so the nt oh stores stay in flight.
// ---------------------------------------------------------------------------
__global__ __launch_bounds__(256, 2) void k1_oh(
    const float* __restrict__ x, const char* __restrict__ wfs,
    const float* __restrict__ b, float* __restrict__ z,
    float* __restrict__ oh)
{
  __shared__ __align__(16) char wbuf[2 * W_CHB];   // 48 KB

  const int t = threadIdx.x, w = t >> 6, l = t & 63;
  const int g = l >> 4, c16 = l & 15;
  const int bm = blockIdx.x;

  f32x4 acc[2][8];
#pragma unroll
  for (int rt = 0; rt < 2; ++rt)
#pragma unroll
    for (int ct = 0; ct < 8; ++ct) acc[rt][ct] = (f32x4){0.f, 0.f, 0.f, 0.f};

  const size_t rowb[2] = {
    ((size_t)bm * 128 + w * 32 + 0 * 16 + c16) * DIN,
    ((size_t)bm * 128 + w * 32 + 1 * 16 + c16) * DIN };

  f32x4 wreg[6];
#pragma unroll
  for (int it = 0; it < 6; ++it)
    wreg[it] = *(const f32x4*)(wfs + it * 4096 + t * 16);
  f32x4 xcur[2][2];
#pragma unroll
  for (int rt = 0; rt < 2; ++rt)
#pragma unroll
    for (int h = 0; h < 2; ++h)
      xcur[rt][h] = *(const f32x4*)(x + rowb[rt] + 4 * g + 16 * h);
#pragma unroll
  for (int it = 0; it < 6; ++it)
    *(f32x4*)(wbuf + it * 4096 + t * 16) = wreg[it];
  __syncthreads();

  for (int kc = 0; kc < 16; ++kc) {
    const char* buf = wbuf + (size_t)(kc & 1) * W_CHB;
    const bool more = (kc + 1) < 16;
    f32x4 xnext[2][2];
    if (more) {
#pragma unroll
      for (int it = 0; it < 6; ++it)
        wreg[it] = *(const f32x4*)(wfs + (size_t)(kc + 1) * W_CHB + it * 4096 + t * 16);
#pragma unroll
      for (int rt = 0; rt < 2; ++rt)
#pragma unroll
        for (int h = 0; h < 2; ++h)
          xnext[rt][h] = *(const f32x4*)(x + rowb[rt] + (kc + 1) * 32 + 4 * g + 16 * h);
    }

    // one-hot zeros for rows kc*8 .. kc*8+7 (streams under the MFMA block;
    // not drained at the lgkmcnt-only barrier)
    {
      float* orow = oh + ((size_t)bm * 128 + kc * 8 + (t >> 5)) * KCB + (t & 31) * 4;
      const f32x4 zv4 = {0.f, 0.f, 0.f, 0.f};
#pragma unroll
      for (int u = 0; u < 8; ++u)
        __builtin_nontemporal_store(zv4, (f32x4*)(orow + u * 128));
    }

    short8 a1[2], a2[2], a3[2];
#pragma unroll
    for (int rt = 0; rt < 2; ++rt)
#pragma unroll
      for (int h = 0; h < 2; ++h)
#pragma unroll
        for (int j = 0; j < 4; ++j) {
          ushort_t q1, q2, q3; split3(xcur[rt][h][j], q1, q2, q3);
          a1[rt][4 * h + j] = (short)q1;
          a2[rt][4 * h + j] = (short)q2;
          a3[rt][4 * h + j] = (short)q3;
        }

#pragma unroll
    for (int ct = 0; ct < 8; ++ct) {
      const char* bp = buf + ct * 1024 + l * 16;
      short8 b1 = *(const short8*)(bp + 0 * W_SPB);
      short8 b2 = *(const short8*)(bp + 1 * W_SPB);
      short8 b3 = *(const short8*)(bp + 2 * W_SPB);
#pragma unroll
      for (int rt = 0; rt < 2; ++rt) {
        f32x4 a = acc[rt][ct];
        a = __builtin_amdgcn_mfma_f32_16x16x32_bf16(as_bf(a1[rt]), as_bf(b1), a, 0, 0, 0);
        a = __builtin_amdgcn_mfma_f32_16x16x32_bf16(as_bf(a1[rt]), as_bf(b2), a, 0, 0, 0);
        a = __builtin_amdgcn_mfma_f32_16x16x32_bf16(as_bf(a2[rt]), as_bf(b1), a, 0, 0, 0);
        a = __builtin_amdgcn_mfma_f32_16x16x32_bf16(as_bf(a1[rt]), as_bf(b3), a, 0, 0, 0);
        a = __builtin_amdgcn_mfma_f32_16x16x32_bf16(as_bf(a2[rt]), as_bf(b2), a, 0, 0, 0);
        a = __builtin_amdgcn_mfma_f32_16x16x32_bf16(as_bf(a3[rt]), as_bf(b1), a, 0, 0, 0);
        acc[rt][ct] = a;
      }
    }

    if (more) {
      char* nbuf = wbuf + (size_t)((kc + 1) & 1) * W_CHB;
#pragma unroll
      for (int it = 0; it < 6; ++it)
        *(f32x4*)(nbuf + it * 4096 + t * 16) = wreg[it];
#pragma unroll
      for (int rt = 0; rt < 2; ++rt)
#pragma unroll
        for (int h = 0; h < 2; ++h) xcur[rt][h] = xnext[rt][h];
    }
    barrier_lds_only();   // was __syncthreads(): keep oh stores in flight
  }

  // epilogue: bias + store z
#pragma unroll
  for (int ct = 0; ct < 8; ++ct) {
    float bb = b[ct * 16 + c16];
#pragma unroll
    for (int rt = 0; rt < 2; ++rt)
#pragma unroll
      for (int i = 0; i < 4; ++i) {
        size_t row = (size_t)bm * 128 + w * 32 + rt * 16 + 4 * g + i;
        z[row * ZDIM + ct * 16 + c16] = acc[rt][ct][i] + bb;
      }
  }
}

// ---------------------------------------------------------------------------
// k2f: two-pass candidate-filtered VQ (round-6 proven structure).
//  pass 1: s1*s1 MFMA -> per-row approx min m^
//  pass 2: replay, gate d^ <= m^ + 0.25*sqrt(A), pool candidates
//  refine: exact f32 dot, u64 CAS-min (first-index tie-break). Then outputs.
// ---------------------------------------------------------------------------
__global__ __launch_bounds__(256, 2) void k2f(
    const float* __restrict__ zc, const float* __restrict__ cbk,
    const char* __restrict__ cbs, const float* __restrict__ cnorm,
    float* __restrict__ zst, float* __restrict__ zq, float* __restrict__ oh)
{
  __shared__ __align__(16) char sm[16384];   // s1 chunk double buffer (2 x 8 KB)
  __shared__ u64_t rowkey[128];
  __shared__ uint_t wpool[4][POOL_CAP];
  __shared__ int wcnt[4];
  __shared__ int karr[128];

  const int t = threadIdx.x, w = t >> 6, l = t & 63;
  const int g = l >> 4, c16 = l & 15;
  const int bm = blockIdx.x;

  if (t < 128) rowkey[t] = ~0ull;
  if (t < 4) wcnt[t] = 0;

  // ---- A-frags (s1 only) + exact row norms ----
  short8 a1f[2][4];
  float anorm[2][4];
#pragma unroll
  for (int rt = 0; rt < 2; ++rt) {
    const size_t rb = ((size_t)bm * 128 + w * 32 + rt * 16 + c16) * ZDIM;
    float psum = 0.f;
#pragma unroll
    for (int ks = 0; ks < 4; ++ks)
#pragma unroll
      for (int h = 0; h < 2; ++h) {
        f32x4 v = *(const f32x4*)(zc + rb + ks * 32 + 4 * g + 16 * h);
#pragma unroll
        for (int j = 0; j < 4; ++j) {
          a1f[rt][ks][4 * h + j] = (short)bf_rtn(v[j]);
          psum += v[j] * v[j];
        }
      }
    psum += __shfl_xor(psum, 16);
    psum += __shfl_xor(psum, 32);
#pragma unroll
    for (int i = 0; i < 4; ++i) anorm[rt][i] = __shfl(psum, 4 * g + i);
  }

  // ================= pass 1: approx min =================
  float m1[2][4];
#pragma unroll
  for (int rt = 0; rt < 2; ++rt)
#pragma unroll
    for (int i = 0; i < 4; ++i) m1[rt][i] = 3.402823466e38f;

  f32x4 streg[2];
#pragma unroll
  for (int it = 0; it < 2; ++it)
    streg[it] = *(const f32x4*)(cbs + it * 4096 + t * 16);
#pragma unroll
  for (int it = 0; it < 2; ++it)
    *(f32x4*)(sm + it * 4096 + t * 16) = streg[it];
  __syncthreads();

  for (int c = 0; c < 32; ++c) {
    const char* buf = sm + (size_t)(c & 1) * 8192;
    const bool more = (c + 1) < 32;
    if (more) {
#pragma unroll
      for (int it = 0; it < 2; ++it)
        streg[it] = *(const f32x4*)(cbs + (size_t)(c + 1) * CB_CHB + it * 4096 + t * 16);
    }
    const float cn0 = cnorm[c * 32 + c16];
    const float cn1 = cnorm[c * 32 + 16 + c16];

#pragma unroll
    for (int ct = 0; ct < 2; ++ct) {
      f32x4 pa[2];
#pragma unroll
      for (int rt = 0; rt < 2; ++rt) pa[rt] = (f32x4){0.f, 0.f, 0.f, 0.f};
#pragma unroll
      for (int ks = 0; ks < 4; ++ks) {
        short8 b1 = *(const short8*)(buf + ct * 4096 + ks * 1024 + l * 16);
#pragma unroll
        for (int rt = 0; rt < 2; ++rt)
          pa[rt] = __builtin_amdgcn_mfma_f32_16x16x32_bf16(as_bf(a1f[rt][ks]), as_bf(b1), pa[rt], 0, 0, 0);
      }
      const float cn = ct ? cn1 : cn0;
#pragma unroll
      for (int rt = 0; rt < 2; ++rt)
#pragma unroll
        for (int i = 0; i < 4; ++i) {
          float f = (anorm[rt][i] - 2.f * pa[rt][i]) + cn;
          m1[rt][i] = fminf(m1[rt][i], f);
        }
    }

    if (more) {
      char* nbuf = sm + (size_t)((c + 1) & 1) * 8192;
#pragma unroll
      for (int it = 0; it < 2; ++it)
        *(f32x4*)(nbuf + it * 4096 + t * 16) = streg[it];
    }
    __syncthreads();
  }

  // cross-lane min within each 16-lane group
#pragma unroll
  for (int m = 1; m < 16; m <<= 1)
#pragma unroll
    for (int rt = 0; rt < 2; ++rt)
#pragma unroll
      for (int i = 0; i < 4; ++i)
        m1[rt][i] = fminf(m1[rt][i], __shfl_xor(m1[rt][i], m));

  float thr[2][4];
#pragma unroll
  for (int rt = 0; rt < 2; ++rt)
#pragma unroll
    for (int i = 0; i < 4; ++i)
      thr[rt][i] = m1[rt][i] + 0.25f * sqrtf(anorm[rt][i]);

  // ================= pass 2: collect candidates =================
#pragma unroll
  for (int it = 0; it < 2; ++it)
    streg[it] = *(const f32x4*)(cbs + it * 4096 + t * 16);
#pragma unroll
  for (int it = 0; it < 2; ++it)
    *(f32x4*)(sm + it * 4096 + t * 16) = streg[it];
  __syncthreads();

  for (int c = 0; c < 32; ++c) {
    const char* buf = sm + (size_t)(c & 1) * 8192;
    const bool more = (c + 1) < 32;
    if (more) {
#pragma unroll
      for (int it = 0; it < 2; ++it)
        streg[it] = *(const f32x4*)(cbs + (size_t)(c + 1) * CB_CHB + it * 4096 + t * 16);
    }
    const float cn0 = cnorm[c * 32 + c16];
    const float cn1 = cnorm[c * 32 + 16 + c16];

#pragma unroll
    for (int ct = 0; ct < 2; ++ct) {
      f32x4 pa[2];
#pragma unroll
      for (int rt = 0; rt < 2; ++rt) pa[rt] = (f32x4){0.f, 0.f, 0.f, 0.f};
#pragma unroll
      for (int ks = 0; ks < 4; ++ks) {
        short8 b1 = *(const short8*)(buf + ct * 4096 + ks * 1024 + l * 16);
#pragma unroll
        for (int rt = 0; rt < 2; ++rt)
          pa[rt] = __builtin_amdgcn_mfma_f32_16x16x32_bf16(as_bf(a1f[rt][ks]), as_bf(b1), pa[rt], 0, 0, 0);
      }
      const float cn = ct ? cn1 : cn0;
      const int colb = c * 32 + ct * 16 + c16;
#pragma unroll
      for (int rt = 0; rt < 2; ++rt)
#pragma unroll
        for (int i = 0; i < 4; ++i) {
          float f = (anorm[rt][i] - 2.f * pa[rt][i]) + cn;
          if (f <= thr[rt][i]) {
            uint_t packed = (uint_t)colb | ((uint_t)(rt * 16 + 4 * g + i) << 10);
            int slot = atomicAdd(&wcnt[w], 1);
            if (slot < POOL_CAP) wpool[w][slot] = packed;
            else refine_one(packed, bm, w, zc, cbk, cnorm, rowkey);  // rare
          }
        }
    }

    if (more) {
      char* nbuf = sm + (size_t)((c + 1) & 1) * 8192;
#pragma unroll
      for (int it = 0; it < 2; ++it)
        *(f32x4*)(nbuf + it * 4096 + t * 16) = streg[it];
    }
    __syncthreads();
  }

  // ================= refine (wave-pooled, lane-parallel) =================
  int cnt = wcnt[w]; if (cnt > POOL_CAP) cnt = POOL_CAP;
  for (int s = l; s < cnt; s += 64)
    refine_one(wpool[w][s], bm, w, zc, cbk, cnorm, rowkey);
  __syncthreads();
  if (t < 128) karr[t] = (int)(rowkey[t] & 1023ull);
  __syncthreads();

  // ---- zst + zq (vectorized gather from L2-resident codebook) ----
#pragma unroll
  for (int it = 0; it < 16; ++it) {
    const int idx = it * 256 + t;
    const int r = idx >> 5, cq = (idx & 31) * 4;
    f32x4 v = *(const f32x4*)&cbk[(size_t)karr[r] * ZDIM + cq];
    const size_t off = ((size_t)bm * 128 + r) * ZDIM + cq;
    __builtin_nontemporal_store(v, (f32x4*)(zst + off));
    __builtin_nontemporal_store(v, (f32x4*)(zq + off));
  }

  // ---- one-hot 1.0 scatter (zeros written by k1_oh) ----
  if (t < 128) {
    oh[(size_t)(bm * 128 + t) * KCB + karr[t]] = 1.0f;
  }
}

// ---------------------------------------------------------------------------
// Fallback path (ws too small): round-1 f32 kernels
// ---------------------------------------------------------------------------
__global__ __launch_bounds__(256) void k1_gemm(
    const float* __restrict__ x, const float* __restrict__ W,
    const float* __restrict__ b, float* __restrict__ z)
{
  __shared__ float xs[32][68];
  __shared__ float ws[32][132];

  const int t  = threadIdx.x;
  const int tx = t & 15, ty = t >> 4;
  const int bm = blockIdx.x;

  float acc[4][8];
#pragma unroll
  for (int i = 0; i < 4; ++i)
#pragma unroll
    for (int j = 0; j < 8; ++j) acc[i][j] = 0.f;

  const int sr  = t >> 2;
  const int skb = (t & 3) * 8;
  const int wkk = t >> 3;
  const int wcol = (t & 7) * 16;

  for (int k0 = 0; k0 < DIN; k0 += 32) {
    float4 v0 = *reinterpret_cast<const float4*>(&x[(size_t)(bm * 64 + sr) * DIN + k0 + skb]);
    float4 v1 = *reinterpret_cast<const float4*>(&x[(size_t)(bm * 64 + sr) * DIN + k0 + skb + 4]);
    xs[skb + 0][sr] = v0.x; xs[skb + 1][sr] = v0.y; xs[skb + 2][sr] = v0.z; xs[skb + 3][sr] = v0.w;
    xs[skb + 4][sr] = v1.x; xs[skb + 5][sr] = v1.y; xs[skb + 6][sr] = v1.z; xs[skb + 7][sr] = v1.w;
#pragma unroll
    for (int u = 0; u < 4; ++u) {
      float4 wv = *reinterpret_cast<const float4*>(&W[(size_t)(k0 + wkk) * ZDIM + wcol + u * 4]);
      *reinterpret_cast<float4*>(&ws[wkk][wcol + u * 4]) = wv;
    }
    __syncthreads();
#pragma unroll
    for (int kk = 0; kk < 32; ++kk) {
      float4 xv = *reinterpret_cast<float4*>(&xs[kk][ty * 4]);
      float4 wa = *reinterpret_cast<float4*>(&ws[kk][tx * 4]);
      float4 wb = *reinterpret_cast<float4*>(&ws[kk][64 + tx * 4]);
      float xr[4] = {xv.x, xv.y, xv.z, xv.w};
      float wr[8] = {wa.x, wa.y, wa.z, wa.w, wb.x, wb.y, wb.z, wb.w};
#pragma unroll
      for (int i = 0; i < 4; ++i)
#pragma unroll
        for (int j = 0; j < 8; ++j) acc[i][j] += xr[i] * wr[j];
    }
    __syncthreads();
  }

  float4 ba = *reinterpret_cast<const float4*>(&b[tx * 4]);
  float4 bb = *reinterpret_cast<const float4*>(&b[64 + tx * 4]);
#pragma unroll
  for (int i = 0; i < 4; ++i) {
    size_t row = (size_t)bm * 64 + ty * 4 + i;
    float4 oa = {acc[i][0] + ba.x, acc[i][1] + ba.y, acc[i][2] + ba.z, acc[i][3] + ba.w};
    float4 ob = {acc[i][4] + bb.x, acc[i][5] + bb.y, acc[i][6] + bb.z, acc[i][7] + bb.w};
    *reinterpret_cast<float4*>(&z[row * ZDIM + tx * 4]) = oa;
    *reinterpret_cast<float4*>(&z[row * ZDIM + 64 + tx * 4]) = ob;
  }
}

__global__ __launch_bounds__(256) void k2_vq(
    const float* __restrict__ zc, const float* __restrict__ cbk,
    float* __restrict__ zst, float* __restrict__ zq, float* __restrict__ oh)
{
  __shared__ float zt[128][68];
  __shared__ float ct[32][132];
  __shared__ float pc[128][2];
  __shared__ float csqc[128];
  __shared__ float Ap[64][4];
  __shared__ float Al[64];
  __shared__ float fbuf[64][17];
  __shared__ int   ibuf[64][17];
  __shared__ int   karr[64];

  const int t  = threadIdx.x;
  const int tx = t & 15, ty = t >> 4;
  const int bm = blockIdx.x;

  {
    const int r = t >> 2, kb = (t & 3) * 32;
    float asum = 0.f;
#pragma unroll
    for (int u = 0; u < 8; ++u) {
      float4 v = *reinterpret_cast<const float4*>(&zc[(size_t)(bm * 64 + r) * ZDIM + kb + u * 4]);
      zt[kb + u * 4 + 0][r] = v.x; zt[kb + u * 4 + 1][r] = v.y;
      zt[kb + u * 4 + 2][r] = v.z; zt[kb + u * 4 + 3][r] = v.w;
      asum += v.x * v.x + v.y * v.y + v.z * v.z + v.w * v.w;
    }
    Ap[r][t & 3] = asum;
  }
  __syncthreads();
  if (t < 64) Al[t] = (Ap[t][0] + Ap[t][1]) + (Ap[t][2] + Ap[t][3]);

  float fmin[4];
  int   kmin[4];
#pragma unroll
  for (int i = 0; i < 4; ++i) { fmin[i] = 3.4e38f; kmin[i] = 0; }

  const int scol = t >> 1, skb = (t & 1) * 16;

  for (int chunk = 0; chunk < 8; ++chunk) {
    float acc[4][8];
#pragma unroll
    for (int i = 0; i < 4; ++i)
#pragma unroll
      for (int j = 0; j < 8; ++j) acc[i][j] = 0.f;
    float cpart = 0.f;

    for (int ks = 0; ks < 4; ++ks) {
      __syncthreads();
#pragma unroll
      for (int u = 0; u < 4; ++u) {
        float4 v = *reinterpret_cast<const float4*>(
            &cbk[(size_t)(chunk * 128 + scol) * ZDIM + ks * 32 + skb + u * 4]);
        ct[skb + u * 4 + 0][scol] = v.x; ct[skb + u * 4 + 1][scol] = v.y;
        ct[skb + u * 4 + 2][scol] = v.z; ct[skb + u * 4 + 3][scol] = v.w;
        cpart += v.x * v.x + v.y * v.y + v.z * v.z + v.w * v.w;
      }
      __syncthreads();
#pragma unroll
      for (int kk = 0; kk < 32; ++kk) {
        float4 xv = *reinterpret_cast<float4*>(&zt[ks * 32 + kk][ty * 4]);
        float4 wa = *reinterpret_cast<float4*>(&ct[kk][tx * 4]);
        float4 wb = *reinterpret_cast<float4*>(&ct[kk][64 + tx * 4]);
        float xr[4] = {xv.x, xv.y, xv.z, xv.w};
        float wr[8] = {wa.x, wa.y, wa.z, wa.w, wb.x, wb.y, wb.z, wb.w};
#pragma unroll
        for (int i = 0; i < 4; ++i)
#pragma unroll
          for (int j = 0; j < 8; ++j) acc[i][j] += xr[i] * wr[j];
      }
    }

    pc[scol][t & 1] = cpart;
    __syncthreads();
    if (t < 128) csqc[t] = pc[t][0] + pc[t][1];
    __syncthreads();

#pragma unroll
    for (int i = 0; i < 4; ++i) {
      float Ar = Al[ty * 4 + i];
#pragma unroll
      for (int j = 0; j < 8; ++j) {
        int colL = (j < 4) ? (tx * 4 + j) : (64 + tx * 4 + (j - 4));
        float B = 2.f * acc[i][j];
        float f = (Ar - B) + csqc[colL];
        int col = chunk * 128 + colL;
        if (f < fmin[i] || (f == fmin[i] && col < kmin[i])) { fmin[i] = f; kmin[i] = col; }
      }
    }
  }

#pragma unroll
  for (int i = 0; i < 4; ++i) { fbuf[ty * 4 + i][tx] = fmin[i]; ibuf[ty * 4 + i][tx] = kmin[i]; }
  __syncthreads();
  if (t < 64) {
    float bf = fbuf[t][0]; int bi = ibuf[t][0];
    for (int e = 1; e < 16; ++e) {
      float f2 = fbuf[t][e]; int i2 = ibuf[t][e];
      if (f2 < bf || (f2 == bf && i2 < bi)) { bf = f2; bi = i2; }
    }
    karr[t] = bi;
  }
  __syncthreads();

  for (int it = 0; it < 32; ++it) {
    int r = it * 2 + (t >> 7);
    int col = t & 127;
    size_t row = (size_t)bm * 64 + r;
    float v = cbk[(size_t)karr[r] * ZDIM + col];
    zst[row * ZDIM + col] = v;
    zq[row * ZDIM + col] = v;
  }

  for (int r = 0; r < 64; ++r) {
    int k = karr[r];
    float4 v = {0.f, 0.f, 0.f, 0.f};
    if ((k >> 2) == t) {
      float* vv = reinterpret_cast<float*>(&v);
      vv[k & 3] = 1.f;
    }
    *reinterpret_cast<float4*>(&oh[(size_t)(bm * 64 + r) * KCB + t * 4]) = v;
  }
}

extern "C" void kernel_launch(void* const* d_in, const int* in_sizes, int n_in,
                              void* d_out, int out_size, void* d_ws, size_t ws_size,
                              hipStream_t stream) {
  const float* x   = (const float*)d_in[0];
  const float* W   = (const float*)d_in[1];
  const float* b   = (const float*)d_in[2];
  const float* cbk = (const float*)d_in[3];

  float* out = (float*)d_out;
  float* zst = out;
  float* zq  = out + (size_t)NROWS * ZDIM;
  float* zc  = out + (size_t)2 * NROWS * ZDIM;
  float* oh  = out + (size_t)3 * NROWS * ZDIM;

  if (ws_size >= (size_t)WS_NEEDED) {
    char* wsb = (char*)d_ws;
    ksplit2<<<KCB, 128, 0, stream>>>(cbk, wsb);
    wsplit<<<256, 256, 0, stream>>>(W, wsb);
    k1_oh<<<NROWS / 128, 256, 0, stream>>>(x, wsb + WF_OFF, b, zc, oh);
    k2f<<<NROWS / 128, 256, 0, stream>>>(
        zc, cbk, wsb, (const float*)(wsb + CNORM_OFF), zst, zq, oh);
  } else {
    k1_gemm<<<NROWS / 64, 256, 0, stream>>>(x, W, b, zc);
    k2_vq<<<NROWS / 64, 256, 0, stream>>>(zc, cbk, zst, zq, oh);
  }
}

// Round 10
// 144.358 us; speedup vs baseline: 1.7305x; 1.0311x over previous
//
#include <hip/hip_runtime.h>
#include <cstddef>

#define NROWS 65536
#define DIN   512
#define ZDIM  128
#define KCB   1024

typedef float  f32x4  __attribute__((ext_vector_type(4)));
typedef short  short8 __attribute__((ext_vector_type(8)));
typedef __bf16 bf16x8 __attribute__((ext_vector_type(8)));
typedef unsigned short ushort_t;
typedef unsigned int   uint_t;
typedef unsigned long long u64_t;

// ---- ws layout ----
#define CB_CHB 24576
#define CB_SPB 8192
#define W_CHB  24576
#define W_SPB  8192
#define CNORM_OFF 786432
#define WF_OFF    790528
#define WS_NEEDED (790528 + 393216)

#define POOL_CAP 128

__device__ inline ushort_t bf_rtn(float v) {
  uint_t u = __float_as_uint(v);
  uint_t r = (u + 0x7fffu + ((u >> 16) & 1u)) >> 16;
  return (ushort_t)r;
}
__device__ inline float bf_up(ushort_t b) { return __uint_as_float(((uint_t)b) << 16); }
__device__ inline bf16x8 as_bf(short8 s) {
  union { short8 s; bf16x8 b; } u; u.s = s; return u.b;
}
__device__ inline void split3(float v, ushort_t& s1, ushort_t& s2, ushort_t& s3) {
  s1 = bf_rtn(v);  float f1 = bf_up(s1);
  float r1 = v - f1; s2 = bf_rtn(r1); float f2 = bf_up(s2);
  float r2 = r1 - f2; s3 = bf_rtn(r2);
}

// producer-side barrier: LDS writes visible, global stores stay in flight
__device__ inline void barrier_lds_only() {
  asm volatile("s_waitcnt lgkmcnt(0)" ::: "memory");
  __builtin_amdgcn_s_barrier();
}

// exact f32 refinement of one (row, col) candidate; CAS-min into rowkey[r]
__device__ inline void refine_one(uint_t packed, int bm, int w,
    const float* __restrict__ zc, const float* __restrict__ cbk,
    const float* __restrict__ cnorm, u64_t* rowkey)
{
  const int col = packed & 1023;
  const int rowloc = (packed >> 10) & 31;
  const int r = w * 32 + rowloc;
  const float* zr = zc + ((size_t)bm * 128 + r) * ZDIM;
  const float* cr = cbk + (size_t)col * ZDIM;
  f32x4 dps = {0.f, 0.f, 0.f, 0.f}, aps = {0.f, 0.f, 0.f, 0.f};
#pragma unroll
  for (int u = 0; u < 32; ++u) {
    f32x4 zv = *(const f32x4*)(zr + u * 4);
    f32x4 cv = *(const f32x4*)(cr + u * 4);
    dps += zv * cv;
    aps += zv * zv;
  }
  float dot = (dps[0] + dps[1]) + (dps[2] + dps[3]);
  float A   = (aps[0] + aps[1]) + (aps[2] + aps[3]);
  float d = (A - 2.f * dot) + cnorm[col];
  uint_t db = __float_as_uint(d);
  db = (db & 0x80000000u) ? ~db : (db | 0x80000000u);   // monotone float->uint
  u64_t key = ((u64_t)db << 32) | (uint_t)col;
  u64_t old = rowkey[r];
  while (key < old) {
    u64_t assumed = old;
    old = atomicCAS(&rowkey[r], assumed, key);
    if (old == assumed) break;
  }
}

// ---------------------------------------------------------------------------
// prep: merged codebook + W 3-way bf16 split (+ ||c||^2).
// grid 1536 x 128: blocks 0..1023 = codebook row n; 1024..1535 = W elements.
// ---------------------------------------------------------------------------
__global__ __launch_bounds__(128) void prep(
    const float* __restrict__ cbk, const float* __restrict__ W,
    char* __restrict__ wsb)
{
  if (blockIdx.x < 1024) {
    const int n = blockIdx.x, k = threadIdx.x;
    float v = cbk[(size_t)n * ZDIM + k];
    ushort_t s1, s2, s3; split3(v, s1, s2, s3);

    const int chunk = n >> 5, ct = (n >> 4) & 1;
    const int km = k & 31, ks = k >> 5;
    const int g = (km >> 2) & 3, h = (km >> 4) & 1, j = (km & 3) + 4 * h;
    const int l = 16 * g + (n & 15);
    char* base = wsb + chunk * CB_CHB + ct * 4096 + ks * 1024 + l * 16 + j * 2;
    *(ushort_t*)(base + 0 * CB_SPB) = s1;
    *(ushort_t*)(base + 1 * CB_SPB) = s2;
    *(ushort_t*)(base + 2 * CB_SPB) = s3;

    float c2 = v * v;
#pragma unroll
    for (int m = 1; m < 64; m <<= 1) c2 += __shfl_xor(c2, m);
    __shared__ float wsum[2];
    if ((threadIdx.x & 63) == 0) wsum[threadIdx.x >> 6] = c2;
    __syncthreads();
    if (threadIdx.x == 0)
      *(float*)(wsb + CNORM_OFF + (size_t)n * 4) = wsum[0] + wsum[1];
  } else {
    const int idx = (blockIdx.x - 1024) * 128 + threadIdx.x;   // 0..65535
    const int k = idx >> 7, col = idx & 127;
    float v = W[(size_t)k * ZDIM + col];
    ushort_t s1, s2, s3; split3(v, s1, s2, s3);

    const int kc = k >> 5, km = k & 31;
    const int g = (km >> 2) & 3, h = (km >> 4) & 1, j = (km & 3) + 4 * h;
    const int ct = col >> 4, l = 16 * g + (col & 15);
    char* base = wsb + WF_OFF + kc * W_CHB + ct * 1024 + l * 16 + j * 2;
    *(ushort_t*)(base + 0 * W_SPB) = s1;
    *(ushort_t*)(base + 1 * W_SPB) = s2;
    *(ushort_t*)(base + 2 * W_SPB) = s3;
  }
}

// ---------------------------------------------------------------------------
// k1_oh: z = x@W+b via 6-product MFMA + one-hot zeros for rows 0..63 of the
// block's 128-row stripe (4 rows/chunk). lgkmcnt-only in-loop barrier.
// ---------------------------------------------------------------------------
__global__ __launch_bounds__(256, 2) void k1_oh(
    const float* __restrict__ x, const char* __restrict__ wfs,
    const float* __restrict__ b, float* __restrict__ z,
    float* __restrict__ oh)
{
  __shared__ __align__(16) char wbuf[2 * W_CHB];   // 48 KB

  const int t = threadIdx.x, w = t >> 6, l = t & 63;
  const int g = l >> 4, c16 = l & 15;
  const int bm = blockIdx.x;

  f32x4 acc[2][8];
#pragma unroll
  for (int rt = 0; rt < 2; ++rt)
#pragma unroll
    for (int ct = 0; ct < 8; ++ct) acc[rt][ct] = (f32x4){0.f, 0.f, 0.f, 0.f};

  const size_t rowb[2] = {
    ((size_t)bm * 128 + w * 32 + 0 * 16 + c16) * DIN,
    ((size_t)bm * 128 + w * 32 + 1 * 16 + c16) * DIN };

  f32x4 wreg[6];
#pragma unroll
  for (int it = 0; it < 6; ++it)
    wreg[it] = *(const f32x4*)(wfs + it * 4096 + t * 16);
  f32x4 xcur[2][2];
#pragma unroll
  for (int rt = 0; rt < 2; ++rt)
#pragma unroll
    for (int h = 0; h < 2; ++h)
      xcur[rt][h] = *(const f32x4*)(x + rowb[rt] + 4 * g + 16 * h);
#pragma unroll
  for (int it = 0; it < 6; ++it)
    *(f32x4*)(wbuf + it * 4096 + t * 16) = wreg[it];
  __syncthreads();

  for (int kc = 0; kc < 16; ++kc) {
    const char* buf = wbuf + (size_t)(kc & 1) * W_CHB;
    const bool more = (kc + 1) < 16;
    f32x4 xnext[2][2];
    if (more) {
#pragma unroll
      for (int it = 0; it < 6; ++it)
        wreg[it] = *(const f32x4*)(wfs + (size_t)(kc + 1) * W_CHB + it * 4096 + t * 16);
#pragma unroll
      for (int rt = 0; rt < 2; ++rt)
#pragma unroll
        for (int h = 0; h < 2; ++h)
          xnext[rt][h] = *(const f32x4*)(x + rowb[rt] + (kc + 1) * 32 + 4 * g + 16 * h);
    }

    // one-hot zeros for rows kc*4 .. kc*4+3 (half stripe; rest in k2f)
    {
      float* orow = oh + ((size_t)bm * 128 + kc * 4 + (t >> 6)) * KCB + (t & 63) * 4;
      const f32x4 zv4 = {0.f, 0.f, 0.f, 0.f};
#pragma unroll
      for (int u = 0; u < 4; ++u)
        __builtin_nontemporal_store(zv4, (f32x4*)(orow + u * 256));
    }

    short8 a1[2], a2[2], a3[2];
#pragma unroll
    for (int rt = 0; rt < 2; ++rt)
#pragma unroll
      for (int h = 0; h < 2; ++h)
#pragma unroll
        for (int j = 0; j < 4; ++j) {
          ushort_t q1, q2, q3; split3(xcur[rt][h][j], q1, q2, q3);
          a1[rt][4 * h + j] = (short)q1;
          a2[rt][4 * h + j] = (short)q2;
          a3[rt][4 * h + j] = (short)q3;
        }

#pragma unroll
    for (int ct = 0; ct < 8; ++ct) {
      const char* bp = buf + ct * 1024 + l * 16;
      short8 b1 = *(const short8*)(bp + 0 * W_SPB);
      short8 b2 = *(const short8*)(bp + 1 * W_SPB);
      short8 b3 = *(const short8*)(bp + 2 * W_SPB);
#pragma unroll
      for (int rt = 0; rt < 2; ++rt) {
        f32x4 a = acc[rt][ct];
        a = __builtin_amdgcn_mfma_f32_16x16x32_bf16(as_bf(a1[rt]), as_bf(b1), a, 0, 0, 0);
        a = __builtin_amdgcn_mfma_f32_16x16x32_bf16(as_bf(a1[rt]), as_bf(b2), a, 0, 0, 0);
        a = __builtin_amdgcn_mfma_f32_16x16x32_bf16(as_bf(a2[rt]), as_bf(b1), a, 0, 0, 0);
        a = __builtin_amdgcn_mfma_f32_16x16x32_bf16(as_bf(a1[rt]), as_bf(b3), a, 0, 0, 0);
        a = __builtin_amdgcn_mfma_f32_16x16x32_bf16(as_bf(a2[rt]), as_bf(b2), a, 0, 0, 0);
        a = __builtin_amdgcn_mfma_f32_16x16x32_bf16(as_bf(a3[rt]), as_bf(b1), a, 0, 0, 0);
        acc[rt][ct] = a;
      }
    }

    if (more) {
      char* nbuf = wbuf + (size_t)((kc + 1) & 1) * W_CHB;
#pragma unroll
      for (int it = 0; it < 6; ++it)
        *(f32x4*)(nbuf + it * 4096 + t * 16) = wreg[it];
#pragma unroll
      for (int rt = 0; rt < 2; ++rt)
#pragma unroll
        for (int h = 0; h < 2; ++h) xcur[rt][h] = xnext[rt][h];
    }
    barrier_lds_only();
  }

  // epilogue: bias + store z
#pragma unroll
  for (int ct = 0; ct < 8; ++ct) {
    float bb = b[ct * 16 + c16];
#pragma unroll
    for (int rt = 0; rt < 2; ++rt)
#pragma unroll
      for (int i = 0; i < 4; ++i) {
        size_t row = (size_t)bm * 128 + w * 32 + rt * 16 + 4 * g + i;
        z[row * ZDIM + ct * 16 + c16] = acc[rt][ct][i] + bb;
      }
  }
}

// ---------------------------------------------------------------------------
// k2f: two-pass candidate-filtered VQ. Pass 1 additionally streams the
// one-hot zeros for rows 64..127 of the block's stripe (2 rows/chunk).
// ---------------------------------------------------------------------------
__global__ __launch_bounds__(256, 2) void k2f(
    const float* __restrict__ zc, const float* __restrict__ cbk,
    const char* __restrict__ cbs, const float* __restrict__ cnorm,
    float* __restrict__ zst, float* __restrict__ zq, float* __restrict__ oh)
{
  __shared__ __align__(16) char sm[16384];   // s1 chunk double buffer (2 x 8 KB)
  __shared__ u64_t rowkey[128];
  __shared__ uint_t wpool[4][POOL_CAP];
  __shared__ int wcnt[4];
  __shared__ int karr[128];

  const int t = threadIdx.x, w = t >> 6, l = t & 63;
  const int g = l >> 4, c16 = l & 15;
  const int bm = blockIdx.x;

  if (t < 128) rowkey[t] = ~0ull;
  if (t < 4) wcnt[t] = 0;

  // ---- A-frags (s1 only) + exact row norms ----
  short8 a1f[2][4];
  float anorm[2][4];
#pragma unroll
  for (int rt = 0; rt < 2; ++rt) {
    const size_t rb = ((size_t)bm * 128 + w * 32 + rt * 16 + c16) * ZDIM;
    float psum = 0.f;
#pragma unroll
    for (int ks = 0; ks < 4; ++ks)
#pragma unroll
      for (int h = 0; h < 2; ++h) {
        f32x4 v = *(const f32x4*)(zc + rb + ks * 32 + 4 * g + 16 * h);
#pragma unroll
        for (int j = 0; j < 4; ++j) {
          a1f[rt][ks][4 * h + j] = (short)bf_rtn(v[j]);
          psum += v[j] * v[j];
        }
      }
    psum += __shfl_xor(psum, 16);
    psum += __shfl_xor(psum, 32);
#pragma unroll
    for (int i = 0; i < 4; ++i) anorm[rt][i] = __shfl(psum, 4 * g + i);
  }

  // ================= pass 1: approx min (+ oh zeros rows 64..127) =========
  float m1[2][4];
#pragma unroll
  for (int rt = 0; rt < 2; ++rt)
#pragma unroll
    for (int i = 0; i < 4; ++i) m1[rt][i] = 3.402823466e38f;

  f32x4 streg[2];
#pragma unroll
  for (int it = 0; it < 2; ++it)
    streg[it] = *(const f32x4*)(cbs + it * 4096 + t * 16);
#pragma unroll
  for (int it = 0; it < 2; ++it)
    *(f32x4*)(sm + it * 4096 + t * 16) = streg[it];
  __syncthreads();

  for (int c = 0; c < 32; ++c) {
    const char* buf = sm + (size_t)(c & 1) * 8192;
    const bool more = (c + 1) < 32;
    if (more) {
#pragma unroll
      for (int it = 0; it < 2; ++it)
        streg[it] = *(const f32x4*)(cbs + (size_t)(c + 1) * CB_CHB + it * 4096 + t * 16);
    }

    // one-hot zeros for rows 64 + c*2 .. +1 (other half written by k1_oh)
    {
      float* orow = oh + ((size_t)bm * 128 + 64 + c * 2 + (t >> 7)) * KCB + (t & 127) * 4;
      const f32x4 zv4 = {0.f, 0.f, 0.f, 0.f};
#pragma unroll
      for (int u = 0; u < 2; ++u)
        __builtin_nontemporal_store(zv4, (f32x4*)(orow + u * 512));
    }

    const float cn0 = cnorm[c * 32 + c16];
    const float cn1 = cnorm[c * 32 + 16 + c16];

#pragma unroll
    for (int ct = 0; ct < 2; ++ct) {
      f32x4 pa[2];
#pragma unroll
      for (int rt = 0; rt < 2; ++rt) pa[rt] = (f32x4){0.f, 0.f, 0.f, 0.f};
#pragma unroll
      for (int ks = 0; ks < 4; ++ks) {
        short8 b1 = *(const short8*)(buf + ct * 4096 + ks * 1024 + l * 16);
#pragma unroll
        for (int rt = 0; rt < 2; ++rt)
          pa[rt] = __builtin_amdgcn_mfma_f32_16x16x32_bf16(as_bf(a1f[rt][ks]), as_bf(b1), pa[rt], 0, 0, 0);
      }
      const float cn = ct ? cn1 : cn0;
#pragma unroll
      for (int rt = 0; rt < 2; ++rt)
#pragma unroll
        for (int i = 0; i < 4; ++i) {
          float f = (anorm[rt][i] - 2.f * pa[rt][i]) + cn;
          m1[rt][i] = fminf(m1[rt][i], f);
        }
    }

    if (more) {
      char* nbuf = sm + (size_t)((c + 1) & 1) * 8192;
#pragma unroll
      for (int it = 0; it < 2; ++it)
        *(f32x4*)(nbuf + it * 4096 + t * 16) = streg[it];
    }
    __syncthreads();
  }

  // cross-lane min within each 16-lane group
#pragma unroll
  for (int m = 1; m < 16; m <<= 1)
#pragma unroll
    for (int rt = 0; rt < 2; ++rt)
#pragma unroll
      for (int i = 0; i < 4; ++i)
        m1[rt][i] = fminf(m1[rt][i], __shfl_xor(m1[rt][i], m));

  float thr[2][4];
#pragma unroll
  for (int rt = 0; rt < 2; ++rt)
#pragma unroll
    for (int i = 0; i < 4; ++i)
      thr[rt][i] = m1[rt][i] + 0.25f * sqrtf(anorm[rt][i]);

  // ================= pass 2: collect candidates =================
#pragma unroll
  for (int it = 0; it < 2; ++it)
    streg[it] = *(const f32x4*)(cbs + it * 4096 + t * 16);
#pragma unroll
  for (int it = 0; it < 2; ++it)
    *(f32x4*)(sm + it * 4096 + t * 16) = streg[it];
  __syncthreads();

  for (int c = 0; c < 32; ++c) {
    const char* buf = sm + (size_t)(c & 1) * 8192;
    const bool more = (c + 1) < 32;
    if (more) {
#pragma unroll
      for (int it = 0; it < 2; ++it)
        streg[it] = *(const f32x4*)(cbs + (size_t)(c + 1) * CB_CHB + it * 4096 + t * 16);
    }
    const float cn0 = cnorm[c * 32 + c16];
    const float cn1 = cnorm[c * 32 + 16 + c16];

#pragma unroll
    for (int ct = 0; ct < 2; ++ct) {
      f32x4 pa[2];
#pragma unroll
      for (int rt = 0; rt < 2; ++rt) pa[rt] = (f32x4){0.f, 0.f, 0.f, 0.f};
#pragma unroll
      for (int ks = 0; ks < 4; ++ks) {
        short8 b1 = *(const short8*)(buf + ct * 4096 + ks * 1024 + l * 16);
#pragma unroll
        for (int rt = 0; rt < 2; ++rt)
          pa[rt] = __builtin_amdgcn_mfma_f32_16x16x32_bf16(as_bf(a1f[rt][ks]), as_bf(b1), pa[rt], 0, 0, 0);
      }
      const float cn = ct ? cn1 : cn0;
      const int colb = c * 32 + ct * 16 + c16;
#pragma unroll
      for (int rt = 0; rt < 2; ++rt)
#pragma unroll
        for (int i = 0; i < 4; ++i) {
          float f = (anorm[rt][i] - 2.f * pa[rt][i]) + cn;
          if (f <= thr[rt][i]) {
            uint_t packed = (uint_t)colb | ((uint_t)(rt * 16 + 4 * g + i) << 10);
            int slot = atomicAdd(&wcnt[w], 1);
            if (slot < POOL_CAP) wpool[w][slot] = packed;
            else refine_one(packed, bm, w, zc, cbk, cnorm, rowkey);  // rare
          }
        }
    }

    if (more) {
      char* nbuf = sm + (size_t)((c + 1) & 1) * 8192;
#pragma unroll
      for (int it = 0; it < 2; ++it)
        *(f32x4*)(nbuf + it * 4096 + t * 16) = streg[it];
    }
    __syncthreads();
  }

  // ================= refine (wave-pooled, lane-parallel) =================
  int cnt = wcnt[w]; if (cnt > POOL_CAP) cnt = POOL_CAP;
  for (int s = l; s < cnt; s += 64)
    refine_one(wpool[w][s], bm, w, zc, cbk, cnorm, rowkey);
  __syncthreads();
  if (t < 128) karr[t] = (int)(rowkey[t] & 1023ull);
  __syncthreads();

  // ---- zst + zq (vectorized gather from L2-resident codebook) ----
#pragma unroll
  for (int it = 0; it < 16; ++it) {
    const int idx = it * 256 + t;
    const int r = idx >> 5, cq = (idx & 31) * 4;
    f32x4 v = *(const f32x4*)&cbk[(size_t)karr[r] * ZDIM + cq];
    const size_t off = ((size_t)bm * 128 + r) * ZDIM + cq;
    __builtin_nontemporal_store(v, (f32x4*)(zst + off));
    __builtin_nontemporal_store(v, (f32x4*)(zq + off));
  }

  // ---- one-hot 1.0 scatter (zeros: rows 0..63 by k1_oh, 64..127 above) ----
  if (t < 128) {
    oh[(size_t)(bm * 128 + t) * KCB + karr[t]] = 1.0f;
  }
}

// ---------------------------------------------------------------------------
// Fallback path (ws too small): round-1 f32 kernels
// ---------------------------------------------------------------------------
__global__ __launch_bounds__(256) void k1_gemm(
    const float* __restrict__ x, const float* __restrict__ W,
    const float* __restrict__ b, float* __restrict__ z)
{
  __shared__ float xs[32][68];
  __shared__ float ws[32][132];

  const int t  = threadIdx.x;
  const int tx = t & 15, ty = t >> 4;
  const int bm = blockIdx.x;

  float acc[4][8];
#pragma unroll
  for (int i = 0; i < 4; ++i)
#pragma unroll
    for (int j = 0; j < 8; ++j) acc[i][j] = 0.f;

  const int sr  = t >> 2;
  const int skb = (t & 3) * 8;
  const int wkk = t >> 3;
  const int wcol = (t & 7) * 16;

  for (int k0 = 0; k0 < DIN; k0 += 32) {
    float4 v0 = *reinterpret_cast<const float4*>(&x[(size_t)(bm * 64 + sr) * DIN + k0 + skb]);
    float4 v1 = *reinterpret_cast<const float4*>(&x[(size_t)(bm * 64 + sr) * DIN + k0 + skb + 4]);
    xs[skb + 0][sr] = v0.x; xs[skb + 1][sr] = v0.y; xs[skb + 2][sr] = v0.z; xs[skb + 3][sr] = v0.w;
    xs[skb + 4][sr] = v1.x; xs[skb + 5][sr] = v1.y; xs[skb + 6][sr] = v1.z; xs[skb + 7][sr] = v1.w;
#pragma unroll
    for (int u = 0; u < 4; ++u) {
      float4 wv = *reinterpret_cast<const float4*>(&W[(size_t)(k0 + wkk) * ZDIM + wcol + u * 4]);
      *reinterpret_cast<float4*>(&ws[wkk][wcol + u * 4]) = wv;
    }
    __syncthreads();
#pragma unroll
    for (int kk = 0; kk < 32; ++kk) {
      float4 xv = *reinterpret_cast<float4*>(&xs[kk][ty * 4]);
      float4 wa = *reinterpret_cast<float4*>(&ws[kk][tx * 4]);
      float4 wb = *reinterpret_cast<float4*>(&ws[kk][64 + tx * 4]);
      float xr[4] = {xv.x, xv.y, xv.z, xv.w};
      float wr[8] = {wa.x, wa.y, wa.z, wa.w, wb.x, wb.y, wb.z, wb.w};
#pragma unroll
      for (int i = 0; i < 4; ++i)
#pragma unroll
        for (int j = 0; j < 8; ++j) acc[i][j] += xr[i] * wr[j];
    }
    __syncthreads();
  }

  float4 ba = *reinterpret_cast<const float4*>(&b[tx * 4]);
  float4 bb = *reinterpret_cast<const float4*>(&b[64 + tx * 4]);
#pragma unroll
  for (int i = 0; i < 4; ++i) {
    size_t row = (size_t)bm * 64 + ty * 4 + i;
    float4 oa = {acc[i][0] + ba.x, acc[i][1] + ba.y, acc[i][2] + ba.z, acc[i][3] + ba.w};
    float4 ob = {acc[i][4] + bb.x, acc[i][5] + bb.y, acc[i][6] + bb.z, acc[i][7] + bb.w};
    *reinterpret_cast<float4*>(&z[row * ZDIM + tx * 4]) = oa;
    *reinterpret_cast<float4*>(&z[row * ZDIM + 64 + tx * 4]) = ob;
  }
}

__global__ __launch_bounds__(256) void k2_vq(
    const float* __restrict__ zc, const float* __restrict__ cbk,
    float* __restrict__ zst, float* __restrict__ zq, float* __restrict__ oh)
{
  __shared__ float zt[128][68];
  __shared__ float ct[32][132];
  __shared__ float pc[128][2];
  __shared__ float csqc[128];
  __shared__ float Ap[64][4];
  __shared__ float Al[64];
  __shared__ float fbuf[64][17];
  __shared__ int   ibuf[64][17];
  __shared__ int   karr[64];

  const int t  = threadIdx.x;
  const int tx = t & 15, ty = t >> 4;
  const int bm = blockIdx.x;

  {
    const int r = t >> 2, kb = (t & 3) * 32;
    float asum = 0.f;
#pragma unroll
    for (int u = 0; u < 8; ++u) {
      float4 v = *reinterpret_cast<const float4*>(&zc[(size_t)(bm * 64 + r) * ZDIM + kb + u * 4]);
      zt[kb + u * 4 + 0][r] = v.x; zt[kb + u * 4 + 1][r] = v.y;
      zt[kb + u * 4 + 2][r] = v.z; zt[kb + u * 4 + 3][r] = v.w;
      asum += v.x * v.x + v.y * v.y + v.z * v.z + v.w * v.w;
    }
    Ap[r][t & 3] = asum;
  }
  __syncthreads();
  if (t < 64) Al[t] = (Ap[t][0] + Ap[t][1]) + (Ap[t][2] + Ap[t][3]);

  float fmin[4];
  int   kmin[4];
#pragma unroll
  for (int i = 0; i < 4; ++i) { fmin[i] = 3.4e38f; kmin[i] = 0; }

  const int scol = t >> 1, skb = (t & 1) * 16;

  for (int chunk = 0; chunk < 8; ++chunk) {
    float acc[4][8];
#pragma unroll
    for (int i = 0; i < 4; ++i)
#pragma unroll
      for (int j = 0; j < 8; ++j) acc[i][j] = 0.f;
    float cpart = 0.f;

    for (int ks = 0; ks < 4; ++ks) {
      __syncthreads();
#pragma unroll
      for (int u = 0; u < 4; ++u) {
        float4 v = *reinterpret_cast<const float4*>(
            &cbk[(size_t)(chunk * 128 + scol) * ZDIM + ks * 32 + skb + u * 4]);
        ct[skb + u * 4 + 0][scol] = v.x; ct[skb + u * 4 + 1][scol] = v.y;
        ct[skb + u * 4 + 2][scol] = v.z; ct[skb + u * 4 + 3][scol] = v.w;
        cpart += v.x * v.x + v.y * v.y + v.z * v.z + v.w * v.w;
      }
      __syncthreads();
#pragma unroll
      for (int kk = 0; kk < 32; ++kk) {
        float4 xv = *reinterpret_cast<float4*>(&zt[ks * 32 + kk][ty * 4]);
        float4 wa = *reinterpret_cast<float4*>(&ct[kk][tx * 4]);
        float4 wb = *reinterpret_cast<float4*>(&ct[kk][64 + tx * 4]);
        float xr[4] = {xv.x, xv.y, xv.z, xv.w};
        float wr[8] = {wa.x, wa.y, wa.z, wa.w, wb.x, wb.y, wb.z, wb.w};
#pragma unroll
        for (int i = 0; i < 4; ++i)
#pragma unroll
          for (int j = 0; j < 8; ++j) acc[i][j] += xr[i] * wr[j];
      }
    }

    pc[scol][t & 1] = cpart;
    __syncthreads();
    if (t < 128) csqc[t] = pc[t][0] + pc[t][1];
    __syncthreads();

#pragma unroll
    for (int i = 0; i < 4; ++i) {
      float Ar = Al[ty * 4 + i];
#pragma unroll
      for (int j = 0; j < 8; ++j) {
        int colL = (j < 4) ? (tx * 4 + j) : (64 + tx * 4 + (j - 4));
        float B = 2.f * acc[i][j];
        float f = (Ar - B) + csqc[colL];
        int col = chunk * 128 + colL;
        if (f < fmin[i] || (f == fmin[i] && col < kmin[i])) { fmin[i] = f; kmin[i] = col; }
      }
    }
  }

#pragma unroll
  for (int i = 0; i < 4; ++i) { fbuf[ty * 4 + i][tx] = fmin[i]; ibuf[ty * 4 + i][tx] = kmin[i]; }
  __syncthreads();
  if (t < 64) {
    float bf = fbuf[t][0]; int bi = ibuf[t][0];
    for (int e = 1; e < 16; ++e) {
      float f2 = fbuf[t][e]; int i2 = ibuf[t][e];
      if (f2 < bf || (f2 == bf && i2 < bi)) { bf = f2; bi = i2; }
    }
    karr[t] = bi;
  }
  __syncthreads();

  for (int it = 0; it < 32; ++it) {
    int r = it * 2 + (t >> 7);
    int col = t & 127;
    size_t row = (size_t)bm * 64 + r;
    float v = cbk[(size_t)karr[r] * ZDIM + col];
    zst[row * ZDIM + col] = v;
    zq[row * ZDIM + col] = v;
  }

  for (int r = 0; r < 64; ++r) {
    int k = karr[r];
    float4 v = {0.f, 0.f, 0.f, 0.f};
    if ((k >> 2) == t) {
      float* vv = reinterpret_cast<float*>(&v);
      vv[k & 3] = 1.f;
    }
    *reinterpret_cast<float4*>(&oh[(size_t)(bm * 64 + r) * KCB + t * 4]) = v;
  }
}

extern "C" void kernel_launch(void* const* d_in, const int* in_sizes, int n_in,
                              void* d_out, int out_size, void* d_ws, size_t ws_size,
                              hipStream_t stream) {
  const float* x   = (const float*)d_in[0];
  const float* W   = (const float*)d_in[1];
  const float* b   = (const float*)d_in[2];
  const float* cbk = (const float*)d_in[3];

  float* out = (float*)d_out;
  float* zst = out;
  float* zq  = out + (size_t)NROWS * ZDIM;
  float* zc  = out + (size_t)2 * NROWS * ZDIM;
  float* oh  = out + (size_t)3 * NROWS * ZDIM;

  if (ws_size >= (size_t)WS_NEEDED) {
    char* wsb = (char*)d_ws;
    prep<<<1536, 128, 0, stream>>>(cbk, W, wsb);
    k1_oh<<<NROWS / 128, 256, 0, stream>>>(x, wsb + WF_OFF, b, zc, oh);
    k2f<<<NROWS / 128, 256, 0, stream>>>(
        zc, cbk, wsb, (const float*)(wsb + CNORM_OFF), zst, zq, oh);
  } else {
    k1_gemm<<<NROWS / 64, 256, 0, stream>>>(x, W, b, zc);
    k2_vq<<<NROWS / 64, 256, 0, stream>>>(zc, cbk, zst, zq, oh);
  }
}

// Round 11
// 141.150 us; speedup vs baseline: 1.7699x; 1.0227x over previous
//
#include <hip/hip_runtime.h>
#include <cstddef>

#define NROWS 65536
#define DIN   512
#define ZDIM  128
#define KCB   1024

typedef float  f32x4  __attribute__((ext_vector_type(4)));
typedef short  short8 __attribute__((ext_vector_type(8)));
typedef __bf16 bf16x8 __attribute__((ext_vector_type(8)));
typedef unsigned short ushort_t;
typedef unsigned int   uint_t;
typedef unsigned long long u64_t;

// ---- ws layout ----
#define CB_CHB 24576
#define CB_SPB 8192
#define W_CHB  24576
#define W_SPB  8192
#define CNORM_OFF 786432
#define WF_OFF    790528
#define WS_NEEDED (790528 + 393216)

#define POOL_CAP 128

__device__ inline ushort_t bf_rtn(float v) {
  uint_t u = __float_as_uint(v);
  uint_t r = (u + 0x7fffu + ((u >> 16) & 1u)) >> 16;
  return (ushort_t)r;
}
__device__ inline float bf_up(ushort_t b) { return __uint_as_float(((uint_t)b) << 16); }
__device__ inline bf16x8 as_bf(short8 s) {
  union { short8 s; bf16x8 b; } u; u.s = s; return u.b;
}
__device__ inline void split3(float v, ushort_t& s1, ushort_t& s2, ushort_t& s3) {
  s1 = bf_rtn(v);  float f1 = bf_up(s1);
  float r1 = v - f1; s2 = bf_rtn(r1); float f2 = bf_up(s2);
  float r2 = r1 - f2; s3 = bf_rtn(r2);
}

// producer-side barrier: LDS writes visible, global stores stay in flight
__device__ inline void barrier_lds_only() {
  asm volatile("s_waitcnt lgkmcnt(0)" ::: "memory");
  __builtin_amdgcn_s_barrier();
}

// exact f32 refinement of one (row, col) candidate; CAS-min into rowkey[r]
__device__ inline void refine_one(uint_t packed, int bm, int w,
    const float* __restrict__ zc, const float* __restrict__ cbk,
    const float* __restrict__ cnorm, u64_t* rowkey)
{
  const int col = packed & 1023;
  const int rowloc = (packed >> 10) & 31;
  const int r = w * 32 + rowloc;
  const float* zr = zc + ((size_t)bm * 128 + r) * ZDIM;
  const float* cr = cbk + (size_t)col * ZDIM;
  f32x4 dps = {0.f, 0.f, 0.f, 0.f}, aps = {0.f, 0.f, 0.f, 0.f};
#pragma unroll
  for (int u = 0; u < 32; ++u) {
    f32x4 zv = *(const f32x4*)(zr + u * 4);
    f32x4 cv = *(const f32x4*)(cr + u * 4);
    dps += zv * cv;
    aps += zv * zv;
  }
  float dot = (dps[0] + dps[1]) + (dps[2] + dps[3]);
  float A   = (aps[0] + aps[1]) + (aps[2] + aps[3]);
  float d = (A - 2.f * dot) + cnorm[col];
  uint_t db = __float_as_uint(d);
  db = (db & 0x80000000u) ? ~db : (db | 0x80000000u);   // monotone float->uint
  u64_t key = ((u64_t)db << 32) | (uint_t)col;
  u64_t old = rowkey[r];
  while (key < old) {
    u64_t assumed = old;
    old = atomicCAS(&rowkey[r], assumed, key);
    if (old == assumed) break;
  }
}

// ---------------------------------------------------------------------------
// prep: merged codebook + W 3-way bf16 split (+ ||c||^2).
// grid 1536 x 128: blocks 0..1023 = codebook row n; 1024..1535 = W elements.
// ---------------------------------------------------------------------------
__global__ __launch_bounds__(128) void prep(
    const float* __restrict__ cbk, const float* __restrict__ W,
    char* __restrict__ wsb)
{
  if (blockIdx.x < 1024) {
    const int n = blockIdx.x, k = threadIdx.x;
    float v = cbk[(size_t)n * ZDIM + k];
    ushort_t s1, s2, s3; split3(v, s1, s2, s3);

    const int chunk = n >> 5, ct = (n >> 4) & 1;
    const int km = k & 31, ks = k >> 5;
    const int g = (km >> 2) & 3, h = (km >> 4) & 1, j = (km & 3) + 4 * h;
    const int l = 16 * g + (n & 15);
    char* base = wsb + chunk * CB_CHB + ct * 4096 + ks * 1024 + l * 16 + j * 2;
    *(ushort_t*)(base + 0 * CB_SPB) = s1;
    *(ushort_t*)(base + 1 * CB_SPB) = s2;
    *(ushort_t*)(base + 2 * CB_SPB) = s3;

    float c2 = v * v;
#pragma unroll
    for (int m = 1; m < 64; m <<= 1) c2 += __shfl_xor(c2, m);
    __shared__ float wsum[2];
    if ((threadIdx.x & 63) == 0) wsum[threadIdx.x >> 6] = c2;
    __syncthreads();
    if (threadIdx.x == 0)
      *(float*)(wsb + CNORM_OFF + (size_t)n * 4) = wsum[0] + wsum[1];
  } else {
    const int idx = (blockIdx.x - 1024) * 128 + threadIdx.x;   // 0..65535
    const int k = idx >> 7, col = idx & 127;
    float v = W[(size_t)k * ZDIM + col];
    ushort_t s1, s2, s3; split3(v, s1, s2, s3);

    const int kc = k >> 5, km = k & 31;
    const int g = (km >> 2) & 3, h = (km >> 4) & 1, j = (km & 3) + 4 * h;
    const int ct = col >> 4, l = 16 * g + (col & 15);
    char* base = wsb + WF_OFF + kc * W_CHB + ct * 1024 + l * 16 + j * 2;
    *(ushort_t*)(base + 0 * W_SPB) = s1;
    *(ushort_t*)(base + 1 * W_SPB) = s2;
    *(ushort_t*)(base + 2 * W_SPB) = s3;
  }
}

// ---------------------------------------------------------------------------
// k1_oh: z = x@W+b via 6-product MFMA + one-hot zeros for rows 0..63 of the
// block's 128-row stripe (4 rows/chunk). lgkmcnt-only in-loop barrier.
// ---------------------------------------------------------------------------
__global__ __launch_bounds__(256, 2) void k1_oh(
    const float* __restrict__ x, const char* __restrict__ wfs,
    const float* __restrict__ b, float* __restrict__ z,
    float* __restrict__ oh)
{
  __shared__ __align__(16) char wbuf[2 * W_CHB];   // 48 KB

  const int t = threadIdx.x, w = t >> 6, l = t & 63;
  const int g = l >> 4, c16 = l & 15;
  const int bm = blockIdx.x;

  f32x4 acc[2][8];
#pragma unroll
  for (int rt = 0; rt < 2; ++rt)
#pragma unroll
    for (int ct = 0; ct < 8; ++ct) acc[rt][ct] = (f32x4){0.f, 0.f, 0.f, 0.f};

  const size_t rowb[2] = {
    ((size_t)bm * 128 + w * 32 + 0 * 16 + c16) * DIN,
    ((size_t)bm * 128 + w * 32 + 1 * 16 + c16) * DIN };

  f32x4 wreg[6];
#pragma unroll
  for (int it = 0; it < 6; ++it)
    wreg[it] = *(const f32x4*)(wfs + it * 4096 + t * 16);
  f32x4 xcur[2][2];
#pragma unroll
  for (int rt = 0; rt < 2; ++rt)
#pragma unroll
    for (int h = 0; h < 2; ++h)
      xcur[rt][h] = *(const f32x4*)(x + rowb[rt] + 4 * g + 16 * h);
#pragma unroll
  for (int it = 0; it < 6; ++it)
    *(f32x4*)(wbuf + it * 4096 + t * 16) = wreg[it];
  __syncthreads();

  for (int kc = 0; kc < 16; ++kc) {
    const char* buf = wbuf + (size_t)(kc & 1) * W_CHB;
    const bool more = (kc + 1) < 16;
    f32x4 xnext[2][2];
    if (more) {
#pragma unroll
      for (int it = 0; it < 6; ++it)
        wreg[it] = *(const f32x4*)(wfs + (size_t)(kc + 1) * W_CHB + it * 4096 + t * 16);
#pragma unroll
      for (int rt = 0; rt < 2; ++rt)
#pragma unroll
        for (int h = 0; h < 2; ++h)
          xnext[rt][h] = *(const f32x4*)(x + rowb[rt] + (kc + 1) * 32 + 4 * g + 16 * h);
    }

    // one-hot zeros for rows kc*4 .. kc*4+3 (half stripe; rest in k2f)
    {
      float* orow = oh + ((size_t)bm * 128 + kc * 4 + (t >> 6)) * KCB + (t & 63) * 4;
      const f32x4 zv4 = {0.f, 0.f, 0.f, 0.f};
#pragma unroll
      for (int u = 0; u < 4; ++u)
        __builtin_nontemporal_store(zv4, (f32x4*)(orow + u * 256));
    }

    short8 a1[2], a2[2], a3[2];
#pragma unroll
    for (int rt = 0; rt < 2; ++rt)
#pragma unroll
      for (int h = 0; h < 2; ++h)
#pragma unroll
        for (int j = 0; j < 4; ++j) {
          ushort_t q1, q2, q3; split3(xcur[rt][h][j], q1, q2, q3);
          a1[rt][4 * h + j] = (short)q1;
          a2[rt][4 * h + j] = (short)q2;
          a3[rt][4 * h + j] = (short)q3;
        }

#pragma unroll
    for (int ct = 0; ct < 8; ++ct) {
      const char* bp = buf + ct * 1024 + l * 16;
      short8 b1 = *(const short8*)(bp + 0 * W_SPB);
      short8 b2 = *(const short8*)(bp + 1 * W_SPB);
      short8 b3 = *(const short8*)(bp + 2 * W_SPB);
#pragma unroll
      for (int rt = 0; rt < 2; ++rt) {
        f32x4 a = acc[rt][ct];
        a = __builtin_amdgcn_mfma_f32_16x16x32_bf16(as_bf(a1[rt]), as_bf(b1), a, 0, 0, 0);
        a = __builtin_amdgcn_mfma_f32_16x16x32_bf16(as_bf(a1[rt]), as_bf(b2), a, 0, 0, 0);
        a = __builtin_amdgcn_mfma_f32_16x16x32_bf16(as_bf(a2[rt]), as_bf(b1), a, 0, 0, 0);
        a = __builtin_amdgcn_mfma_f32_16x16x32_bf16(as_bf(a1[rt]), as_bf(b3), a, 0, 0, 0);
        a = __builtin_amdgcn_mfma_f32_16x16x32_bf16(as_bf(a2[rt]), as_bf(b2), a, 0, 0, 0);
        a = __builtin_amdgcn_mfma_f32_16x16x32_bf16(as_bf(a3[rt]), as_bf(b1), a, 0, 0, 0);
        acc[rt][ct] = a;
      }
    }

    if (more) {
      char* nbuf = wbuf + (size_t)((kc + 1) & 1) * W_CHB;
#pragma unroll
      for (int it = 0; it < 6; ++it)
        *(f32x4*)(nbuf + it * 4096 + t * 16) = wreg[it];
#pragma unroll
      for (int rt = 0; rt < 2; ++rt)
#pragma unroll
        for (int h = 0; h < 2; ++h) xcur[rt][h] = xnext[rt][h];
    }
    barrier_lds_only();
  }

  // epilogue: bias + store z
#pragma unroll
  for (int ct = 0; ct < 8; ++ct) {
    float bb = b[ct * 16 + c16];
#pragma unroll
    for (int rt = 0; rt < 2; ++rt)
#pragma unroll
      for (int i = 0; i < 4; ++i) {
        size_t row = (size_t)bm * 128 + w * 32 + rt * 16 + 4 * g + i;
        z[row * ZDIM + ct * 16 + c16] = acc[rt][ct][i] + bb;
      }
  }
}

// ---------------------------------------------------------------------------
// k2f: two-pass candidate-filtered VQ, 64-col (double-chunk) iterations:
// half the barriers, lgkmcnt-only in-loop barrier (nt stores stream free).
// Pass 1 also streams one-hot zeros for rows 64..127 (4 rows/iter).
// ---------------------------------------------------------------------------
__global__ __launch_bounds__(256, 2) void k2f(
    const float* __restrict__ zc, const float* __restrict__ cbk,
    const char* __restrict__ cbs, const float* __restrict__ cnorm,
    float* __restrict__ zst, float* __restrict__ zq, float* __restrict__ oh)
{
  __shared__ __align__(16) char sm[2 * 16384];   // double-chunk double buffer
  __shared__ u64_t rowkey[128];
  __shared__ uint_t wpool[4][POOL_CAP];
  __shared__ int wcnt[4];
  __shared__ int karr[128];

  const int t = threadIdx.x, w = t >> 6, l = t & 63;
  const int g = l >> 4, c16 = l & 15;
  const int bm = blockIdx.x;

  if (t < 128) rowkey[t] = ~0ull;
  if (t < 4) wcnt[t] = 0;

  // ---- A-frags (s1 only) + exact row norms ----
  short8 a1f[2][4];
  float anorm[2][4];
#pragma unroll
  for (int rt = 0; rt < 2; ++rt) {
    const size_t rb = ((size_t)bm * 128 + w * 32 + rt * 16 + c16) * ZDIM;
    float psum = 0.f;
#pragma unroll
    for (int ks = 0; ks < 4; ++ks)
#pragma unroll
      for (int h = 0; h < 2; ++h) {
        f32x4 v = *(const f32x4*)(zc + rb + ks * 32 + 4 * g + 16 * h);
#pragma unroll
        for (int j = 0; j < 4; ++j) {
          a1f[rt][ks][4 * h + j] = (short)bf_rtn(v[j]);
          psum += v[j] * v[j];
        }
      }
    psum += __shfl_xor(psum, 16);
    psum += __shfl_xor(psum, 32);
#pragma unroll
    for (int i = 0; i < 4; ++i) anorm[rt][i] = __shfl(psum, 4 * g + i);
  }

  // ================= pass 1: approx min (+ oh zeros rows 64..127) =========
  float m1[2][4];
#pragma unroll
  for (int rt = 0; rt < 2; ++rt)
#pragma unroll
    for (int i = 0; i < 4; ++i) m1[rt][i] = 3.402823466e38f;

  f32x4 streg[4];
#pragma unroll
  for (int hc = 0; hc < 2; ++hc)
#pragma unroll
    for (int it = 0; it < 2; ++it)
      streg[hc * 2 + it] = *(const f32x4*)(cbs + (size_t)hc * CB_CHB + it * 4096 + t * 16);
#pragma unroll
  for (int it = 0; it < 4; ++it)
    *(f32x4*)(sm + it * 4096 + t * 16) = streg[it];
  __syncthreads();

  for (int cc = 0; cc < 16; ++cc) {
    const char* buf = sm + (size_t)(cc & 1) * 16384;
    const bool more = (cc + 1) < 16;
    if (more) {
#pragma unroll
      for (int hc = 0; hc < 2; ++hc)
#pragma unroll
        for (int it = 0; it < 2; ++it)
          streg[hc * 2 + it] = *(const f32x4*)(
              cbs + (size_t)(cc * 2 + 2 + hc) * CB_CHB + it * 4096 + t * 16);
    }

    // one-hot zeros for rows 64 + cc*4 .. +3
    {
      float* orow = oh + ((size_t)bm * 128 + 64 + cc * 4 + (t >> 6)) * KCB + (t & 63) * 4;
      const f32x4 zv4 = {0.f, 0.f, 0.f, 0.f};
#pragma unroll
      for (int u = 0; u < 4; ++u)
        __builtin_nontemporal_store(zv4, (f32x4*)(orow + u * 256));
    }

#pragma unroll
    for (int ch = 0; ch < 2; ++ch) {
      const int c = cc * 2 + ch;
      const float cn0 = cnorm[c * 32 + c16];
      const float cn1 = cnorm[c * 32 + 16 + c16];
#pragma unroll
      for (int ct = 0; ct < 2; ++ct) {
        f32x4 pa[2];
#pragma unroll
        for (int rt = 0; rt < 2; ++rt) pa[rt] = (f32x4){0.f, 0.f, 0.f, 0.f};
#pragma unroll
        for (int ks = 0; ks < 4; ++ks) {
          short8 b1 = *(const short8*)(buf + ch * 8192 + ct * 4096 + ks * 1024 + l * 16);
#pragma unroll
          for (int rt = 0; rt < 2; ++rt)
            pa[rt] = __builtin_amdgcn_mfma_f32_16x16x32_bf16(as_bf(a1f[rt][ks]), as_bf(b1), pa[rt], 0, 0, 0);
        }
        const float cn = ct ? cn1 : cn0;
#pragma unroll
        for (int rt = 0; rt < 2; ++rt)
#pragma unroll
          for (int i = 0; i < 4; ++i) {
            float f = (anorm[rt][i] - 2.f * pa[rt][i]) + cn;
            m1[rt][i] = fminf(m1[rt][i], f);
          }
      }
    }

    if (more) {
      char* nbuf = sm + (size_t)((cc + 1) & 1) * 16384;
#pragma unroll
      for (int it = 0; it < 4; ++it)
        *(f32x4*)(nbuf + it * 4096 + t * 16) = streg[it];
    }
    barrier_lds_only();
  }

  // cross-lane min within each 16-lane group
#pragma unroll
  for (int m = 1; m < 16; m <<= 1)
#pragma unroll
    for (int rt = 0; rt < 2; ++rt)
#pragma unroll
      for (int i = 0; i < 4; ++i)
        m1[rt][i] = fminf(m1[rt][i], __shfl_xor(m1[rt][i], m));

  float thr[2][4];
#pragma unroll
  for (int rt = 0; rt < 2; ++rt)
#pragma unroll
    for (int i = 0; i < 4; ++i)
      thr[rt][i] = m1[rt][i] + 0.25f * sqrtf(anorm[rt][i]);

  // ================= pass 2: collect candidates =================
#pragma unroll
  for (int hc = 0; hc < 2; ++hc)
#pragma unroll
    for (int it = 0; it < 2; ++it)
      streg[hc * 2 + it] = *(const f32x4*)(cbs + (size_t)hc * CB_CHB + it * 4096 + t * 16);
#pragma unroll
  for (int it = 0; it < 4; ++it)
    *(f32x4*)(sm + it * 4096 + t * 16) = streg[it];
  __syncthreads();

  for (int cc = 0; cc < 16; ++cc) {
    const char* buf = sm + (size_t)(cc & 1) * 16384;
    const bool more = (cc + 1) < 16;
    if (more) {
#pragma unroll
      for (int hc = 0; hc < 2; ++hc)
#pragma unroll
        for (int it = 0; it < 2; ++it)
          streg[hc * 2 + it] = *(const f32x4*)(
              cbs + (size_t)(cc * 2 + 2 + hc) * CB_CHB + it * 4096 + t * 16);
    }

#pragma unroll
    for (int ch = 0; ch < 2; ++ch) {
      const int c = cc * 2 + ch;
      const float cn0 = cnorm[c * 32 + c16];
      const float cn1 = cnorm[c * 32 + 16 + c16];
#pragma unroll
      for (int ct = 0; ct < 2; ++ct) {
        f32x4 pa[2];
#pragma unroll
        for (int rt = 0; rt < 2; ++rt) pa[rt] = (f32x4){0.f, 0.f, 0.f, 0.f};
#pragma unroll
        for (int ks = 0; ks < 4; ++ks) {
          short8 b1 = *(const short8*)(buf + ch * 8192 + ct * 4096 + ks * 1024 + l * 16);
#pragma unroll
          for (int rt = 0; rt < 2; ++rt)
            pa[rt] = __builtin_amdgcn_mfma_f32_16x16x32_bf16(as_bf(a1f[rt][ks]), as_bf(b1), pa[rt], 0, 0, 0);
        }
        const float cn = ct ? cn1 : cn0;
        const int colb = c * 32 + ct * 16 + c16;
#pragma unroll
        for (int rt = 0; rt < 2; ++rt)
#pragma unroll
          for (int i = 0; i < 4; ++i) {
            float f = (anorm[rt][i] - 2.f * pa[rt][i]) + cn;
            if (f <= thr[rt][i]) {
              uint_t packed = (uint_t)colb | ((uint_t)(rt * 16 + 4 * g + i) << 10);
              int slot = atomicAdd(&wcnt[w], 1);
              if (slot < POOL_CAP) wpool[w][slot] = packed;
              else refine_one(packed, bm, w, zc, cbk, cnorm, rowkey);  // rare
            }
          }
      }
    }

    if (more) {
      char* nbuf = sm + (size_t)((cc + 1) & 1) * 16384;
#pragma unroll
      for (int it = 0; it < 4; ++it)
        *(f32x4*)(nbuf + it * 4096 + t * 16) = streg[it];
    }
    barrier_lds_only();
  }

  // ================= refine (wave-pooled, lane-parallel) =================
  int cnt = wcnt[w]; if (cnt > POOL_CAP) cnt = POOL_CAP;
  for (int s = l; s < cnt; s += 64)
    refine_one(wpool[w][s], bm, w, zc, cbk, cnorm, rowkey);
  __syncthreads();
  if (t < 128) karr[t] = (int)(rowkey[t] & 1023ull);
  __syncthreads();

  // ---- zst + zq (vectorized gather from L2-resident codebook) ----
#pragma unroll
  for (int it = 0; it < 16; ++it) {
    const int idx = it * 256 + t;
    const int r = idx >> 5, cq = (idx & 31) * 4;
    f32x4 v = *(const f32x4*)&cbk[(size_t)karr[r] * ZDIM + cq];
    const size_t off = ((size_t)bm * 128 + r) * ZDIM + cq;
    __builtin_nontemporal_store(v, (f32x4*)(zst + off));
    __builtin_nontemporal_store(v, (f32x4*)(zq + off));
  }

  // ---- one-hot 1.0 scatter (zeros: rows 0..63 by k1_oh, 64..127 above) ----
  if (t < 128) {
    oh[(size_t)(bm * 128 + t) * KCB + karr[t]] = 1.0f;
  }
}

// ---------------------------------------------------------------------------
// Fallback path (ws too small): round-1 f32 kernels
// ---------------------------------------------------------------------------
__global__ __launch_bounds__(256) void k1_gemm(
    const float* __restrict__ x, const float* __restrict__ W,
    const float* __restrict__ b, float* __restrict__ z)
{
  __shared__ float xs[32][68];
  __shared__ float ws[32][132];

  const int t  = threadIdx.x;
  const int tx = t & 15, ty = t >> 4;
  const int bm = blockIdx.x;

  float acc[4][8];
#pragma unroll
  for (int i = 0; i < 4; ++i)
#pragma unroll
    for (int j = 0; j < 8; ++j) acc[i][j] = 0.f;

  const int sr  = t >> 2;
  const int skb = (t & 3) * 8;
  const int wkk = t >> 3;
  const int wcol = (t & 7) * 16;

  for (int k0 = 0; k0 < DIN; k0 += 32) {
    float4 v0 = *reinterpret_cast<const float4*>(&x[(size_t)(bm * 64 + sr) * DIN + k0 + skb]);
    float4 v1 = *reinterpret_cast<const float4*>(&x[(size_t)(bm * 64 + sr) * DIN + k0 + skb + 4]);
    xs[skb + 0][sr] = v0.x; xs[skb + 1][sr] = v0.y; xs[skb + 2][sr] = v0.z; xs[skb + 3][sr] = v0.w;
    xs[skb + 4][sr] = v1.x; xs[skb + 5][sr] = v1.y; xs[skb + 6][sr] = v1.z; xs[skb + 7][sr] = v1.w;
#pragma unroll
    for (int u = 0; u < 4; ++u) {
      float4 wv = *reinterpret_cast<const float4*>(&W[(size_t)(k0 + wkk) * ZDIM + wcol + u * 4]);
      *reinterpret_cast<float4*>(&ws[wkk][wcol + u * 4]) = wv;
    }
    __syncthreads();
#pragma unroll
    for (int kk = 0; kk < 32; ++kk) {
      float4 xv = *reinterpret_cast<float4*>(&xs[kk][ty * 4]);
      float4 wa = *reinterpret_cast<float4*>(&ws[kk][tx * 4]);
      float4 wb = *reinterpret_cast<float4*>(&ws[kk][64 + tx * 4]);
      float xr[4] = {xv.x, xv.y, xv.z, xv.w};
      float wr[8] = {wa.x, wa.y, wa.z, wa.w, wb.x, wb.y, wb.z, wb.w};
#pragma unroll
      for (int i = 0; i < 4; ++i)
#pragma unroll
        for (int j = 0; j < 8; ++j) acc[i][j] += xr[i] * wr[j];
    }
    __syncthreads();
  }

  float4 ba = *reinterpret_cast<const float4*>(&b[tx * 4]);
  float4 bb = *reinterpret_cast<const float4*>(&b[64 + tx * 4]);
#pragma unroll
  for (int i = 0; i < 4; ++i) {
    size_t row = (size_t)bm * 64 + ty * 4 + i;
    float4 oa = {acc[i][0] + ba.x, acc[i][1] + ba.y, acc[i][2] + ba.z, acc[i][3] + ba.w};
    float4 ob = {acc[i][4] + bb.x, acc[i][5] + bb.y, acc[i][6] + bb.z, acc[i][7] + bb.w};
    *reinterpret_cast<float4*>(&z[row * ZDIM + tx * 4]) = oa;
    *reinterpret_cast<float4*>(&z[row * ZDIM + 64 + tx * 4]) = ob;
  }
}

__global__ __launch_bounds__(256) void k2_vq(
    const float* __restrict__ zc, const float* __restrict__ cbk,
    float* __restrict__ zst, float* __restrict__ zq, float* __restrict__ oh)
{
  __shared__ float zt[128][68];
  __shared__ float ct[32][132];
  __shared__ float pc[128][2];
  __shared__ float csqc[128];
  __shared__ float Ap[64][4];
  __shared__ float Al[64];
  __shared__ float fbuf[64][17];
  __shared__ int   ibuf[64][17];
  __shared__ int   karr[64];

  const int t  = threadIdx.x;
  const int tx = t & 15, ty = t >> 4;
  const int bm = blockIdx.x;

  {
    const int r = t >> 2, kb = (t & 3) * 32;
    float asum = 0.f;
#pragma unroll
    for (int u = 0; u < 8; ++u) {
      float4 v = *reinterpret_cast<const float4*>(&zc[(size_t)(bm * 64 + r) * ZDIM + kb + u * 4]);
      zt[kb + u * 4 + 0][r] = v.x; zt[kb + u * 4 + 1][r] = v.y;
      zt[kb + u * 4 + 2][r] = v.z; zt[kb + u * 4 + 3][r] = v.w;
      asum += v.x * v.x + v.y * v.y + v.z * v.z + v.w * v.w;
    }
    Ap[r][t & 3] = asum;
  }
  __syncthreads();
  if (t < 64) Al[t] = (Ap[t][0] + Ap[t][1]) + (Ap[t][2] + Ap[t][3]);

  float fmin[4];
  int   kmin[4];
#pragma unroll
  for (int i = 0; i < 4; ++i) { fmin[i] = 3.4e38f; kmin[i] = 0; }

  const int scol = t >> 1, skb = (t & 1) * 16;

  for (int chunk = 0; chunk < 8; ++chunk) {
    float acc[4][8];
#pragma unroll
    for (int i = 0; i < 4; ++i)
#pragma unroll
      for (int j = 0; j < 8; ++j) acc[i][j] = 0.f;
    float cpart = 0.f;

    for (int ks = 0; ks < 4; ++ks) {
      __syncthreads();
#pragma unroll
      for (int u = 0; u < 4; ++u) {
        float4 v = *reinterpret_cast<const float4*>(
            &cbk[(size_t)(chunk * 128 + scol) * ZDIM + ks * 32 + skb + u * 4]);
        ct[skb + u * 4 + 0][scol] = v.x; ct[skb + u * 4 + 1][scol] = v.y;
        ct[skb + u * 4 + 2][scol] = v.z; ct[skb + u * 4 + 3][scol] = v.w;
        cpart += v.x * v.x + v.y * v.y + v.z * v.z + v.w * v.w;
      }
      __syncthreads();
#pragma unroll
      for (int kk = 0; kk < 32; ++kk) {
        float4 xv = *reinterpret_cast<float4*>(&zt[ks * 32 + kk][ty * 4]);
        float4 wa = *reinterpret_cast<float4*>(&ct[kk][tx * 4]);
        float4 wb = *reinterpret_cast<float4*>(&ct[kk][64 + tx * 4]);
        float xr[4] = {xv.x, xv.y, xv.z, xv.w};
        float wr[8] = {wa.x, wa.y, wa.z, wa.w, wb.x, wb.y, wb.z, wb.w};
#pragma unroll
        for (int i = 0; i < 4; ++i)
#pragma unroll
          for (int j = 0; j < 8; ++j) acc[i][j] += xr[i] * wr[j];
      }
    }

    pc[scol][t & 1] = cpart;
    __syncthreads();
    if (t < 128) csqc[t] = pc[t][0] + pc[t][1];
    __syncthreads();

#pragma unroll
    for (int i = 0; i < 4; ++i) {
      float Ar = Al[ty * 4 + i];
#pragma unroll
      for (int j = 0; j < 8; ++j) {
        int colL = (j < 4) ? (tx * 4 + j) : (64 + tx * 4 + (j - 4));
        float B = 2.f * acc[i][j];
        float f = (Ar - B) + csqc[colL];
        int col = chunk * 128 + colL;
        if (f < fmin[i] || (f == fmin[i] && col < kmin[i])) { fmin[i] = f; kmin[i] = col; }
      }
    }
  }

#pragma unroll
  for (int i = 0; i < 4; ++i) { fbuf[ty * 4 + i][tx] = fmin[i]; ibuf[ty * 4 + i][tx] = kmin[i]; }
  __syncthreads();
  if (t < 64) {
    float bf = fbuf[t][0]; int bi = ibuf[t][0];
    for (int e = 1; e < 16; ++e) {
      float f2 = fbuf[t][e]; int i2 = ibuf[t][e];
      if (f2 < bf || (f2 == bf && i2 < bi)) { bf = f2; bi = i2; }
    }
    karr[t] = bi;
  }
  __syncthreads();

  for (int it = 0; it < 32; ++it) {
    int r = it * 2 + (t >> 7);
    int col = t & 127;
    size_t row = (size_t)bm * 64 + r;
    float v = cbk[(size_t)karr[r] * ZDIM + col];
    zst[row * ZDIM + col] = v;
    zq[row * ZDIM + col] = v;
  }

  for (int r = 0; r < 64; ++r) {
    int k = karr[r];
    float4 v = {0.f, 0.f, 0.f, 0.f};
    if ((k >> 2) == t) {
      float* vv = reinterpret_cast<float*>(&v);
      vv[k & 3] = 1.f;
    }
    *reinterpret_cast<float4*>(&oh[(size_t)(bm * 64 + r) * KCB + t * 4]) = v;
  }
}

extern "C" void kernel_launch(void* const* d_in, const int* in_sizes, int n_in,
                              void* d_out, int out_size, void* d_ws, size_t ws_size,
                              hipStream_t stream) {
  const float* x   = (const float*)d_in[0];
  const float* W   = (const float*)d_in[1];
  const float* b   = (const float*)d_in[2];
  const float* cbk = (const float*)d_in[3];

  float* out = (float*)d_out;
  float* zst = out;
  float* zq  = out + (size_t)NROWS * ZDIM;
  float* zc  = out + (size_t)2 * NROWS * ZDIM;
  float* oh  = out + (size_t)3 * NROWS * ZDIM;

  if (ws_size >= (size_t)WS_NEEDED) {
    char* wsb = (char*)d_ws;
    prep<<<1536, 128, 0, stream>>>(cbk, W, wsb);
    k1_oh<<<NROWS / 128, 256, 0, stream>>>(x, wsb + WF_OFF, b, zc, oh);
    k2f<<<NROWS / 128, 256, 0, stream>>>(
        zc, cbk, wsb, (const float*)(wsb + CNORM_OFF), zst, zq, oh);
  } else {
    k1_gemm<<<NROWS / 64, 256, 0, stream>>>(x, W, b, zc);
    k2_vq<<<NROWS / 64, 256, 0, stream>>>(zc, cbk, zst, zq, oh);
  }
}

// Round 12
// 137.818 us; speedup vs baseline: 1.8126x; 1.0242x over previous
//
#include <hip/hip_runtime.h>
#include <cstddef>

#define NROWS 65536
#define DIN   512
#define ZDIM  128
#define KCB   1024

typedef float  f32x4  __attribute__((ext_vector_type(4)));
typedef short  short8 __attribute__((ext_vector_type(8)));
typedef __bf16 bf16x8 __attribute__((ext_vector_type(8)));
typedef unsigned short ushort_t;
typedef unsigned int   uint_t;
typedef unsigned long long u64_t;

// ---- ws layout ----
#define CB_CHB 24576
#define CB_SPB 8192
#define W_CHB  24576
#define W_SPB  8192
#define CNORM_OFF 786432
#define WF_OFF    790528
#define WS_NEEDED (790528 + 393216)

#define POOL_CAP 128

__device__ inline ushort_t bf_rtn(float v) {
  uint_t u = __float_as_uint(v);
  uint_t r = (u + 0x7fffu + ((u >> 16) & 1u)) >> 16;
  return (ushort_t)r;
}
__device__ inline float bf_up(ushort_t b) { return __uint_as_float(((uint_t)b) << 16); }
__device__ inline bf16x8 as_bf(short8 s) {
  union { short8 s; bf16x8 b; } u; u.s = s; return u.b;
}
__device__ inline void split3(float v, ushort_t& s1, ushort_t& s2, ushort_t& s3) {
  s1 = bf_rtn(v);  float f1 = bf_up(s1);
  float r1 = v - f1; s2 = bf_rtn(r1); float f2 = bf_up(s2);
  float r2 = r1 - f2; s3 = bf_rtn(r2);
}

// producer-side barrier: LDS writes visible, global stores stay in flight
__device__ inline void barrier_lds_only() {
  asm volatile("s_waitcnt lgkmcnt(0)" ::: "memory");
  __builtin_amdgcn_s_barrier();
}

// exact f32 refinement of one (row, col) candidate; CAS-min into rowkey[r]
__device__ inline void refine_one(uint_t packed, int bm, int w,
    const float* __restrict__ zc, const float* __restrict__ cbk,
    const float* __restrict__ cnorm, u64_t* rowkey)
{
  const int col = packed & 1023;
  const int rowloc = (packed >> 10) & 31;
  const int r = w * 32 + rowloc;
  const float* zr = zc + ((size_t)bm * 128 + r) * ZDIM;
  const float* cr = cbk + (size_t)col * ZDIM;
  f32x4 dps = {0.f, 0.f, 0.f, 0.f}, aps = {0.f, 0.f, 0.f, 0.f};
#pragma unroll
  for (int u = 0; u < 32; ++u) {
    f32x4 zv = *(const f32x4*)(zr + u * 4);
    f32x4 cv = *(const f32x4*)(cr + u * 4);
    dps += zv * cv;
    aps += zv * zv;
  }
  float dot = (dps[0] + dps[1]) + (dps[2] + dps[3]);
  float A   = (aps[0] + aps[1]) + (aps[2] + aps[3]);
  float d = (A - 2.f * dot) + cnorm[col];
  uint_t db = __float_as_uint(d);
  db = (db & 0x80000000u) ? ~db : (db | 0x80000000u);   // monotone float->uint
  u64_t key = ((u64_t)db << 32) | (uint_t)col;
  u64_t old = rowkey[r];
  while (key < old) {
    u64_t assumed = old;
    old = atomicCAS(&rowkey[r], assumed, key);
    if (old == assumed) break;
  }
}

// ---------------------------------------------------------------------------
// prep: merged codebook + W 3-way bf16 split (+ ||c||^2).
// grid 1536 x 128: blocks 0..1023 = codebook row n; 1024..1535 = W elements.
// ---------------------------------------------------------------------------
__global__ __launch_bounds__(128) void prep(
    const float* __restrict__ cbk, const float* __restrict__ W,
    char* __restrict__ wsb)
{
  if (blockIdx.x < 1024) {
    const int n = blockIdx.x, k = threadIdx.x;
    float v = cbk[(size_t)n * ZDIM + k];
    ushort_t s1, s2, s3; split3(v, s1, s2, s3);

    const int chunk = n >> 5, ct = (n >> 4) & 1;
    const int km = k & 31, ks = k >> 5;
    const int g = (km >> 2) & 3, h = (km >> 4) & 1, j = (km & 3) + 4 * h;
    const int l = 16 * g + (n & 15);
    char* base = wsb + chunk * CB_CHB + ct * 4096 + ks * 1024 + l * 16 + j * 2;
    *(ushort_t*)(base + 0 * CB_SPB) = s1;
    *(ushort_t*)(base + 1 * CB_SPB) = s2;
    *(ushort_t*)(base + 2 * CB_SPB) = s3;

    float c2 = v * v;
#pragma unroll
    for (int m = 1; m < 64; m <<= 1) c2 += __shfl_xor(c2, m);
    __shared__ float wsum[2];
    if ((threadIdx.x & 63) == 0) wsum[threadIdx.x >> 6] = c2;
    __syncthreads();
    if (threadIdx.x == 0)
      *(float*)(wsb + CNORM_OFF + (size_t)n * 4) = wsum[0] + wsum[1];
  } else {
    const int idx = (blockIdx.x - 1024) * 128 + threadIdx.x;   // 0..65535
    const int k = idx >> 7, col = idx & 127;
    float v = W[(size_t)k * ZDIM + col];
    ushort_t s1, s2, s3; split3(v, s1, s2, s3);

    const int kc = k >> 5, km = k & 31;
    const int g = (km >> 2) & 3, h = (km >> 4) & 1, j = (km & 3) + 4 * h;
    const int ct = col >> 4, l = 16 * g + (col & 15);
    char* base = wsb + WF_OFF + kc * W_CHB + ct * 1024 + l * 16 + j * 2;
    *(ushort_t*)(base + 0 * W_SPB) = s1;
    *(ushort_t*)(base + 1 * W_SPB) = s2;
    *(ushort_t*)(base + 2 * W_SPB) = s3;
  }
}

// ---------------------------------------------------------------------------
// k1_oh: z = x@W+b via 6-product MFMA + one-hot zeros for rows 0..63.
// SINGLE-buffered 24 KB LDS (reg-prefetch covers the dbuf role) ->
// 6 blocks/CU resident for TLP; two lgkm-only barriers per chunk.
// ---------------------------------------------------------------------------
__global__ __launch_bounds__(256, 2) void k1_oh(
    const float* __restrict__ x, const char* __restrict__ wfs,
    const float* __restrict__ b, float* __restrict__ z,
    float* __restrict__ oh)
{
  __shared__ __align__(16) char wbuf[W_CHB];   // 24 KB single buffer

  const int t = threadIdx.x, w = t >> 6, l = t & 63;
  const int g = l >> 4, c16 = l & 15;
  const int bm = blockIdx.x;

  f32x4 acc[2][8];
#pragma unroll
  for (int rt = 0; rt < 2; ++rt)
#pragma unroll
    for (int ct = 0; ct < 8; ++ct) acc[rt][ct] = (f32x4){0.f, 0.f, 0.f, 0.f};

  const size_t rowb[2] = {
    ((size_t)bm * 128 + w * 32 + 0 * 16 + c16) * DIN,
    ((size_t)bm * 128 + w * 32 + 1 * 16 + c16) * DIN };

  f32x4 wreg[6];
#pragma unroll
  for (int it = 0; it < 6; ++it)
    wreg[it] = *(const f32x4*)(wfs + it * 4096 + t * 16);
  f32x4 xcur[2][2];
#pragma unroll
  for (int rt = 0; rt < 2; ++rt)
#pragma unroll
    for (int h = 0; h < 2; ++h)
      xcur[rt][h] = *(const f32x4*)(x + rowb[rt] + 4 * g + 16 * h);
#pragma unroll
  for (int it = 0; it < 6; ++it)
    *(f32x4*)(wbuf + it * 4096 + t * 16) = wreg[it];
  __syncthreads();

  for (int kc = 0; kc < 16; ++kc) {
    const bool more = (kc + 1) < 16;
    f32x4 xnext[2][2];
    if (more) {
#pragma unroll
      for (int it = 0; it < 6; ++it)
        wreg[it] = *(const f32x4*)(wfs + (size_t)(kc + 1) * W_CHB + it * 4096 + t * 16);
#pragma unroll
      for (int rt = 0; rt < 2; ++rt)
#pragma unroll
        for (int h = 0; h < 2; ++h)
          xnext[rt][h] = *(const f32x4*)(x + rowb[rt] + (kc + 1) * 32 + 4 * g + 16 * h);
    }

    // one-hot zeros for rows kc*4 .. kc*4+3 (half stripe; rest in k2f)
    {
      float* orow = oh + ((size_t)bm * 128 + kc * 4 + (t >> 6)) * KCB + (t & 63) * 4;
      const f32x4 zv4 = {0.f, 0.f, 0.f, 0.f};
#pragma unroll
      for (int u = 0; u < 4; ++u)
        __builtin_nontemporal_store(zv4, (f32x4*)(orow + u * 256));
    }

    short8 a1[2], a2[2], a3[2];
#pragma unroll
    for (int rt = 0; rt < 2; ++rt)
#pragma unroll
      for (int h = 0; h < 2; ++h)
#pragma unroll
        for (int j = 0; j < 4; ++j) {
          ushort_t q1, q2, q3; split3(xcur[rt][h][j], q1, q2, q3);
          a1[rt][4 * h + j] = (short)q1;
          a2[rt][4 * h + j] = (short)q2;
          a3[rt][4 * h + j] = (short)q3;
        }

#pragma unroll
    for (int ct = 0; ct < 8; ++ct) {
      const char* bp = wbuf + ct * 1024 + l * 16;
      short8 b1 = *(const short8*)(bp + 0 * W_SPB);
      short8 b2 = *(const short8*)(bp + 1 * W_SPB);
      short8 b3 = *(const short8*)(bp + 2 * W_SPB);
#pragma unroll
      for (int rt = 0; rt < 2; ++rt) {
        f32x4 a = acc[rt][ct];
        a = __builtin_amdgcn_mfma_f32_16x16x32_bf16(as_bf(a1[rt]), as_bf(b1), a, 0, 0, 0);
        a = __builtin_amdgcn_mfma_f32_16x16x32_bf16(as_bf(a1[rt]), as_bf(b2), a, 0, 0, 0);
        a = __builtin_amdgcn_mfma_f32_16x16x32_bf16(as_bf(a2[rt]), as_bf(b1), a, 0, 0, 0);
        a = __builtin_amdgcn_mfma_f32_16x16x32_bf16(as_bf(a1[rt]), as_bf(b3), a, 0, 0, 0);
        a = __builtin_amdgcn_mfma_f32_16x16x32_bf16(as_bf(a2[rt]), as_bf(b2), a, 0, 0, 0);
        a = __builtin_amdgcn_mfma_f32_16x16x32_bf16(as_bf(a3[rt]), as_bf(b1), a, 0, 0, 0);
        acc[rt][ct] = a;
      }
    }

    if (more) {
      barrier_lds_only();   // all waves' reads of wbuf complete
#pragma unroll
      for (int it = 0; it < 6; ++it)
        *(f32x4*)(wbuf + it * 4096 + t * 16) = wreg[it];
#pragma unroll
      for (int rt = 0; rt < 2; ++rt)
#pragma unroll
        for (int h = 0; h < 2; ++h) xcur[rt][h] = xnext[rt][h];
      barrier_lds_only();   // new chunk visible to all
    }
  }

  // epilogue: bias + store z
#pragma unroll
  for (int ct = 0; ct < 8; ++ct) {
    float bb = b[ct * 16 + c16];
#pragma unroll
    for (int rt = 0; rt < 2; ++rt)
#pragma unroll
      for (int i = 0; i < 4; ++i) {
        size_t row = (size_t)bm * 128 + w * 32 + rt * 16 + 4 * g + i;
        z[row * ZDIM + ct * 16 + c16] = acc[rt][ct][i] + bb;
      }
  }
}

// ---------------------------------------------------------------------------
// k2f: two-pass candidate-filtered VQ, 64-col (double-chunk) iterations:
// half the barriers, lgkmcnt-only in-loop barrier (nt stores stream free).
// Pass 1 also streams one-hot zeros for rows 64..127 (4 rows/iter).
// ---------------------------------------------------------------------------
__global__ __launch_bounds__(256, 2) void k2f(
    const float* __restrict__ zc, const float* __restrict__ cbk,
    const char* __restrict__ cbs, const float* __restrict__ cnorm,
    float* __restrict__ zst, float* __restrict__ zq, float* __restrict__ oh)
{
  __shared__ __align__(16) char sm[2 * 16384];   // double-chunk double buffer
  __shared__ u64_t rowkey[128];
  __shared__ uint_t wpool[4][POOL_CAP];
  __shared__ int wcnt[4];
  __shared__ int karr[128];

  const int t = threadIdx.x, w = t >> 6, l = t & 63;
  const int g = l >> 4, c16 = l & 15;
  const int bm = blockIdx.x;

  if (t < 128) rowkey[t] = ~0ull;
  if (t < 4) wcnt[t] = 0;

  // ---- A-frags (s1 only) + exact row norms ----
  short8 a1f[2][4];
  float anorm[2][4];
#pragma unroll
  for (int rt = 0; rt < 2; ++rt) {
    const size_t rb = ((size_t)bm * 128 + w * 32 + rt * 16 + c16) * ZDIM;
    float psum = 0.f;
#pragma unroll
    for (int ks = 0; ks < 4; ++ks)
#pragma unroll
      for (int h = 0; h < 2; ++h) {
        f32x4 v = *(const f32x4*)(zc + rb + ks * 32 + 4 * g + 16 * h);
#pragma unroll
        for (int j = 0; j < 4; ++j) {
          a1f[rt][ks][4 * h + j] = (short)bf_rtn(v[j]);
          psum += v[j] * v[j];
        }
      }
    psum += __shfl_xor(psum, 16);
    psum += __shfl_xor(psum, 32);
#pragma unroll
    for (int i = 0; i < 4; ++i) anorm[rt][i] = __shfl(psum, 4 * g + i);
  }

  // ================= pass 1: approx min (+ oh zeros rows 64..127) =========
  float m1[2][4];
#pragma unroll
  for (int rt = 0; rt < 2; ++rt)
#pragma unroll
    for (int i = 0; i < 4; ++i) m1[rt][i] = 3.402823466e38f;

  f32x4 streg[4];
#pragma unroll
  for (int hc = 0; hc < 2; ++hc)
#pragma unroll
    for (int it = 0; it < 2; ++it)
      streg[hc * 2 + it] = *(const f32x4*)(cbs + (size_t)hc * CB_CHB + it * 4096 + t * 16);
#pragma unroll
  for (int it = 0; it < 4; ++it)
    *(f32x4*)(sm + it * 4096 + t * 16) = streg[it];
  __syncthreads();

  for (int cc = 0; cc < 16; ++cc) {
    const char* buf = sm + (size_t)(cc & 1) * 16384;
    const bool more = (cc + 1) < 16;
    if (more) {
#pragma unroll
      for (int hc = 0; hc < 2; ++hc)
#pragma unroll
        for (int it = 0; it < 2; ++it)
          streg[hc * 2 + it] = *(const f32x4*)(
              cbs + (size_t)(cc * 2 + 2 + hc) * CB_CHB + it * 4096 + t * 16);
    }

    // one-hot zeros for rows 64 + cc*4 .. +3
    {
      float* orow = oh + ((size_t)bm * 128 + 64 + cc * 4 + (t >> 6)) * KCB + (t & 63) * 4;
      const f32x4 zv4 = {0.f, 0.f, 0.f, 0.f};
#pragma unroll
      for (int u = 0; u < 4; ++u)
        __builtin_nontemporal_store(zv4, (f32x4*)(orow + u * 256));
    }

#pragma unroll
    for (int ch = 0; ch < 2; ++ch) {
      const int c = cc * 2 + ch;
      const float cn0 = cnorm[c * 32 + c16];
      const float cn1 = cnorm[c * 32 + 16 + c16];
#pragma unroll
      for (int ct = 0; ct < 2; ++ct) {
        f32x4 pa[2];
#pragma unroll
        for (int rt = 0; rt < 2; ++rt) pa[rt] = (f32x4){0.f, 0.f, 0.f, 0.f};
#pragma unroll
        for (int ks = 0; ks < 4; ++ks) {
          short8 b1 = *(const short8*)(buf + ch * 8192 + ct * 4096 + ks * 1024 + l * 16);
#pragma unroll
          for (int rt = 0; rt < 2; ++rt)
            pa[rt] = __builtin_amdgcn_mfma_f32_16x16x32_bf16(as_bf(a1f[rt][ks]), as_bf(b1), pa[rt], 0, 0, 0);
        }
        const float cn = ct ? cn1 : cn0;
#pragma unroll
        for (int rt = 0; rt < 2; ++rt)
#pragma unroll
          for (int i = 0; i < 4; ++i) {
            float f = (anorm[rt][i] - 2.f * pa[rt][i]) + cn;
            m1[rt][i] = fminf(m1[rt][i], f);
          }
      }
    }

    if (more) {
      char* nbuf = sm + (size_t)((cc + 1) & 1) * 16384;
#pragma unroll
      for (int it = 0; it < 4; ++it)
        *(f32x4*)(nbuf + it * 4096 + t * 16) = streg[it];
    }
    barrier_lds_only();
  }

  // cross-lane min within each 16-lane group
#pragma unroll
  for (int m = 1; m < 16; m <<= 1)
#pragma unroll
    for (int rt = 0; rt < 2; ++rt)
#pragma unroll
      for (int i = 0; i < 4; ++i)
        m1[rt][i] = fminf(m1[rt][i], __shfl_xor(m1[rt][i], m));

  float thr[2][4];
#pragma unroll
  for (int rt = 0; rt < 2; ++rt)
#pragma unroll
    for (int i = 0; i < 4; ++i)
      thr[rt][i] = m1[rt][i] + 0.25f * sqrtf(anorm[rt][i]);

  // ================= pass 2: collect candidates =================
#pragma unroll
  for (int hc = 0; hc < 2; ++hc)
#pragma unroll
    for (int it = 0; it < 2; ++it)
      streg[hc * 2 + it] = *(const f32x4*)(cbs + (size_t)hc * CB_CHB + it * 4096 + t * 16);
#pragma unroll
  for (int it = 0; it < 4; ++it)
    *(f32x4*)(sm + it * 4096 + t * 16) = streg[it];
  __syncthreads();

  for (int cc = 0; cc < 16; ++cc) {
    const char* buf = sm + (size_t)(cc & 1) * 16384;
    const bool more = (cc + 1) < 16;
    if (more) {
#pragma unroll
      for (int hc = 0; hc < 2; ++hc)
#pragma unroll
        for (int it = 0; it < 2; ++it)
          streg[hc * 2 + it] = *(const f32x4*)(
              cbs + (size_t)(cc * 2 + 2 + hc) * CB_CHB + it * 4096 + t * 16);
    }

#pragma unroll
    for (int ch = 0; ch < 2; ++ch) {
      const int c = cc * 2 + ch;
      const float cn0 = cnorm[c * 32 + c16];
      const float cn1 = cnorm[c * 32 + 16 + c16];
#pragma unroll
      for (int ct = 0; ct < 2; ++ct) {
        f32x4 pa[2];
#pragma unroll
        for (int rt = 0; rt < 2; ++rt) pa[rt] = (f32x4){0.f, 0.f, 0.f, 0.f};
#pragma unroll
        for (int ks = 0; ks < 4; ++ks) {
          short8 b1 = *(const short8*)(buf + ch * 8192 + ct * 4096 + ks * 1024 + l * 16);
#pragma unroll
          for (int rt = 0; rt < 2; ++rt)
            pa[rt] = __builtin_amdgcn_mfma_f32_16x16x32_bf16(as_bf(a1f[rt][ks]), as_bf(b1), pa[rt], 0, 0, 0);
        }
        const float cn = ct ? cn1 : cn0;
        const int colb = c * 32 + ct * 16 + c16;
#pragma unroll
        for (int rt = 0; rt < 2; ++rt)
#pragma unroll
          for (int i = 0; i < 4; ++i) {
            float f = (anorm[rt][i] - 2.f * pa[rt][i]) + cn;
            if (f <= thr[rt][i]) {
              uint_t packed = (uint_t)colb | ((uint_t)(rt * 16 + 4 * g + i) << 10);
              int slot = atomicAdd(&wcnt[w], 1);
              if (slot < POOL_CAP) wpool[w][slot] = packed;
              else refine_one(packed, bm, w, zc, cbk, cnorm, rowkey);  // rare
            }
          }
      }
    }

    if (more) {
      char* nbuf = sm + (size_t)((cc + 1) & 1) * 16384;
#pragma unroll
      for (int it = 0; it < 4; ++it)
        *(f32x4*)(nbuf + it * 4096 + t * 16) = streg[it];
    }
    barrier_lds_only();
  }

  // ================= refine (wave-pooled, lane-parallel) =================
  int cnt = wcnt[w]; if (cnt > POOL_CAP) cnt = POOL_CAP;
  for (int s = l; s < cnt; s += 64)
    refine_one(wpool[w][s], bm, w, zc, cbk, cnorm, rowkey);
  __syncthreads();
  if (t < 128) karr[t] = (int)(rowkey[t] & 1023ull);
  __syncthreads();

  // ---- zst + zq (vectorized gather from L2-resident codebook) ----
#pragma unroll
  for (int it = 0; it < 16; ++it) {
    const int idx = it * 256 + t;
    const int r = idx >> 5, cq = (idx & 31) * 4;
    f32x4 v = *(const f32x4*)&cbk[(size_t)karr[r] * ZDIM + cq];
    const size_t off = ((size_t)bm * 128 + r) * ZDIM + cq;
    __builtin_nontemporal_store(v, (f32x4*)(zst + off));
    __builtin_nontemporal_store(v, (f32x4*)(zq + off));
  }

  // ---- one-hot 1.0 scatter (zeros: rows 0..63 by k1_oh, 64..127 above) ----
  if (t < 128) {
    oh[(size_t)(bm * 128 + t) * KCB + karr[t]] = 1.0f;
  }
}

// ---------------------------------------------------------------------------
// Fallback path (ws too small): round-1 f32 kernels
// ---------------------------------------------------------------------------
__global__ __launch_bounds__(256) void k1_gemm(
    const float* __restrict__ x, const float* __restrict__ W,
    const float* __restrict__ b, float* __restrict__ z)
{
  __shared__ float xs[32][68];
  __shared__ float ws[32][132];

  const int t  = threadIdx.x;
  const int tx = t & 15, ty = t >> 4;
  const int bm = blockIdx.x;

  float acc[4][8];
#pragma unroll
  for (int i = 0; i < 4; ++i)
#pragma unroll
    for (int j = 0; j < 8; ++j) acc[i][j] = 0.f;

  const int sr  = t >> 2;
  const int skb = (t & 3) * 8;
  const int wkk = t >> 3;
  const int wcol = (t & 7) * 16;

  for (int k0 = 0; k0 < DIN; k0 += 32) {
    float4 v0 = *reinterpret_cast<const float4*>(&x[(size_t)(bm * 64 + sr) * DIN + k0 + skb]);
    float4 v1 = *reinterpret_cast<const float4*>(&x[(size_t)(bm * 64 + sr) * DIN + k0 + skb + 4]);
    xs[skb + 0][sr] = v0.x; xs[skb + 1][sr] = v0.y; xs[skb + 2][sr] = v0.z; xs[skb + 3][sr] = v0.w;
    xs[skb + 4][sr] = v1.x; xs[skb + 5][sr] = v1.y; xs[skb + 6][sr] = v1.z; xs[skb + 7][sr] = v1.w;
#pragma unroll
    for (int u = 0; u < 4; ++u) {
      float4 wv = *reinterpret_cast<const float4*>(&W[(size_t)(k0 + wkk) * ZDIM + wcol + u * 4]);
      *reinterpret_cast<float4*>(&ws[wkk][wcol + u * 4]) = wv;
    }
    __syncthreads();
#pragma unroll
    for (int kk = 0; kk < 32; ++kk) {
      float4 xv = *reinterpret_cast<float4*>(&xs[kk][ty * 4]);
      float4 wa = *reinterpret_cast<float4*>(&ws[kk][tx * 4]);
      float4 wb = *reinterpret_cast<float4*>(&ws[kk][64 + tx * 4]);
      float xr[4] = {xv.x, xv.y, xv.z, xv.w};
      float wr[8] = {wa.x, wa.y, wa.z, wa.w, wb.x, wb.y, wb.z, wb.w};
#pragma unroll
      for (int i = 0; i < 4; ++i)
#pragma unroll
        for (int j = 0; j < 8; ++j) acc[i][j] += xr[i] * wr[j];
    }
    __syncthreads();
  }

  float4 ba = *reinterpret_cast<const float4*>(&b[tx * 4]);
  float4 bb = *reinterpret_cast<const float4*>(&b[64 + tx * 4]);
#pragma unroll
  for (int i = 0; i < 4; ++i) {
    size_t row = (size_t)bm * 64 + ty * 4 + i;
    float4 oa = {acc[i][0] + ba.x, acc[i][1] + ba.y, acc[i][2] + ba.z, acc[i][3] + ba.w};
    float4 ob = {acc[i][4] + bb.x, acc[i][5] + bb.y, acc[i][6] + bb.z, acc[i][7] + bb.w};
    *reinterpret_cast<float4*>(&z[row * ZDIM + tx * 4]) = oa;
    *reinterpret_cast<float4*>(&z[row * ZDIM + 64 + tx * 4]) = ob;
  }
}

__global__ __launch_bounds__(256) void k2_vq(
    const float* __restrict__ zc, const float* __restrict__ cbk,
    float* __restrict__ zst, float* __restrict__ zq, float* __restrict__ oh)
{
  __shared__ float zt[128][68];
  __shared__ float ct[32][132];
  __shared__ float pc[128][2];
  __shared__ float csqc[128];
  __shared__ float Ap[64][4];
  __shared__ float Al[64];
  __shared__ float fbuf[64][17];
  __shared__ int   ibuf[64][17];
  __shared__ int   karr[64];

  const int t  = threadIdx.x;
  const int tx = t & 15, ty = t >> 4;
  const int bm = blockIdx.x;

  {
    const int r = t >> 2, kb = (t & 3) * 32;
    float asum = 0.f;
#pragma unroll
    for (int u = 0; u < 8; ++u) {
      float4 v = *reinterpret_cast<const float4*>(&zc[(size_t)(bm * 64 + r) * ZDIM + kb + u * 4]);
      zt[kb + u * 4 + 0][r] = v.x; zt[kb + u * 4 + 1][r] = v.y;
      zt[kb + u * 4 + 2][r] = v.z; zt[kb + u * 4 + 3][r] = v.w;
      asum += v.x * v.x + v.y * v.y + v.z * v.z + v.w * v.w;
    }
    Ap[r][t & 3] = asum;
  }
  __syncthreads();
  if (t < 64) Al[t] = (Ap[t][0] + Ap[t][1]) + (Ap[t][2] + Ap[t][3]);

  float fmin[4];
  int   kmin[4];
#pragma unroll
  for (int i = 0; i < 4; ++i) { fmin[i] = 3.4e38f; kmin[i] = 0; }

  const int scol = t >> 1, skb = (t & 1) * 16;

  for (int chunk = 0; chunk < 8; ++chunk) {
    float acc[4][8];
#pragma unroll
    for (int i = 0; i < 4; ++i)
#pragma unroll
      for (int j = 0; j < 8; ++j) acc[i][j] = 0.f;
    float cpart = 0.f;

    for (int ks = 0; ks < 4; ++ks) {
      __syncthreads();
#pragma unroll
      for (int u = 0; u < 4; ++u) {
        float4 v = *reinterpret_cast<const float4*>(
            &cbk[(size_t)(chunk * 128 + scol) * ZDIM + ks * 32 + skb + u * 4]);
        ct[skb + u * 4 + 0][scol] = v.x; ct[skb + u * 4 + 1][scol] = v.y;
        ct[skb + u * 4 + 2][scol] = v.z; ct[skb + u * 4 + 3][scol] = v.w;
        cpart += v.x * v.x + v.y * v.y + v.z * v.z + v.w * v.w;
      }
      __syncthreads();
#pragma unroll
      for (int kk = 0; kk < 32; ++kk) {
        float4 xv = *reinterpret_cast<float4*>(&zt[ks * 32 + kk][ty * 4]);
        float4 wa = *reinterpret_cast<float4*>(&ct[kk][tx * 4]);
        float4 wb = *reinterpret_cast<float4*>(&ct[kk][64 + tx * 4]);
        float xr[4] = {xv.x, xv.y, xv.z, xv.w};
        float wr[8] = {wa.x, wa.y, wa.z, wa.w, wb.x, wb.y, wb.z, wb.w};
#pragma unroll
        for (int i = 0; i < 4; ++i)
#pragma unroll
          for (int j = 0; j < 8; ++j) acc[i][j] += xr[i] * wr[j];
      }
    }

    pc[scol][t & 1] = cpart;
    __syncthreads();
    if (t < 128) csqc[t] = pc[t][0] + pc[t][1];
    __syncthreads();

#pragma unroll
    for (int i = 0; i < 4; ++i) {
      float Ar = Al[ty * 4 + i];
#pragma unroll
      for (int j = 0; j < 8; ++j) {
        int colL = (j < 4) ? (tx * 4 + j) : (64 + tx * 4 + (j - 4));
        float B = 2.f * acc[i][j];
        float f = (Ar - B) + csqc[colL];
        int col = chunk * 128 + colL;
        if (f < fmin[i] || (f == fmin[i] && col < kmin[i])) { fmin[i] = f; kmin[i] = col; }
      }
    }
  }

#pragma unroll
  for (int i = 0; i < 4; ++i) { fbuf[ty * 4 + i][tx] = fmin[i]; ibuf[ty * 4 + i][tx] = kmin[i]; }
  __syncthreads();
  if (t < 64) {
    float bf = fbuf[t][0]; int bi = ibuf[t][0];
    for (int e = 1; e < 16; ++e) {
      float f2 = fbuf[t][e]; int i2 = ibuf[t][e];
      if (f2 < bf || (f2 == bf && i2 < bi)) { bf = f2; bi = i2; }
    }
    karr[t] = bi;
  }
  __syncthreads();

  for (int it = 0; it < 32; ++it) {
    int r = it * 2 + (t >> 7);
    int col = t & 127;
    size_t row = (size_t)bm * 64 + r;
    float v = cbk[(size_t)karr[r] * ZDIM + col];
    zst[row * ZDIM + col] = v;
    zq[row * ZDIM + col] = v;
  }

  for (int r = 0; r < 64; ++r) {
    int k = karr[r];
    float4 v = {0.f, 0.f, 0.f, 0.f};
    if ((k >> 2) == t) {
      float* vv = reinterpret_cast<float*>(&v);
      vv[k & 3] = 1.f;
    }
    *reinterpret_cast<float4*>(&oh[(size_t)(bm * 64 + r) * KCB + t * 4]) = v;
  }
}

extern "C" void kernel_launch(void* const* d_in, const int* in_sizes, int n_in,
                              void* d_out, int out_size, void* d_ws, size_t ws_size,
                              hipStream_t stream) {
  const float* x   = (const float*)d_in[0];
  const float* W   = (const float*)d_in[1];
  const float* b   = (const float*)d_in[2];
  const float* cbk = (const float*)d_in[3];

  float* out = (float*)d_out;
  float* zst = out;
  float* zq  = out + (size_t)NROWS * ZDIM;
  float* zc  = out + (size_t)2 * NROWS * ZDIM;
  float* oh  = out + (size_t)3 * NROWS * ZDIM;

  if (ws_size >= (size_t)WS_NEEDED) {
    char* wsb = (char*)d_ws;
    prep<<<1536, 128, 0, stream>>>(cbk, W, wsb);
    k1_oh<<<NROWS / 128, 256, 0, stream>>>(x, wsb + WF_OFF, b, zc, oh);
    k2f<<<NROWS / 128, 256, 0, stream>>>(
        zc, cbk, wsb, (const float*)(wsb + CNORM_OFF), zst, zq, oh);
  } else {
    k1_gemm<<<NROWS / 64, 256, 0, stream>>>(x, W, b, zc);
    k2_vq<<<NROWS / 64, 256, 0, stream>>>(zc, cbk, zst, zq, oh);
  }
}